// Round 11
// baseline (578.278 us; speedup 1.0000x reference)
//
#include <hip/hip_runtime.h>
#include <hip/hip_bf16.h>

#define B_ 4
#define S_ 96
#define T_ 96
#define D_ 512
#define H_ 8
#define FF_ 2048
#define NROWS (B_*S_*T_)   // 36864
#define EPS_ 1e-5f
#define NEG_ 0.01f
#define DD_ (512*512)

typedef unsigned short u16;   // bf16 bits
typedef __attribute__((ext_vector_type(8))) short bf16x8;
typedef __attribute__((ext_vector_type(4))) float f32x4;
typedef __attribute__((address_space(1))) const unsigned glb_u32;
typedef __attribute__((address_space(3))) unsigned lds_u32;

__device__ __forceinline__ float bf(u16 u) { return __uint_as_float(((unsigned)u) << 16); }
__device__ __forceinline__ u16 f2bf(float f) {
    __hip_bfloat16 h = __float2bfloat16(f);
    return *reinterpret_cast<u16*>(&h);
}
__device__ __forceinline__ float blo(unsigned v) { return __uint_as_float(v << 16); }
__device__ __forceinline__ float bhi(unsigned v) { return __uint_as_float(v & 0xffff0000u); }

__device__ __forceinline__ float cvt_ld(float x) { return x; }
__device__ __forceinline__ float cvt_ld(u16 x)  { return bf(x); }
__device__ __forceinline__ void cvt_st(float* p, float v) { *p = v; }
__device__ __forceinline__ void cvt_st(u16* p, float v)   { *p = f2bf(v); }

__device__ __forceinline__ void load8(const float* p, float* y) {
    float4 a = *(const float4*)p, b = *(const float4*)(p + 4);
    y[0]=a.x; y[1]=a.y; y[2]=a.z; y[3]=a.w; y[4]=b.x; y[5]=b.y; y[6]=b.z; y[7]=b.w;
}
__device__ __forceinline__ void load8(const u16* p, float* y) {
    uint4 u = *(const uint4*)p;
    y[0]=blo(u.x); y[1]=bhi(u.x); y[2]=blo(u.y); y[3]=bhi(u.y);
    y[4]=blo(u.z); y[5]=bhi(u.z); y[6]=blo(u.w); y[7]=bhi(u.w);
}
__device__ __forceinline__ void store8(float* p, const float* y) {
    *(float4*)p       = make_float4(y[0], y[1], y[2], y[3]);
    *(float4*)(p + 4) = make_float4(y[4], y[5], y[6], y[7]);
}
__device__ __forceinline__ void store8(u16* p, const float* y) {
    ushort4 a, b;
    a.x = f2bf(y[0]); a.y = f2bf(y[1]); a.z = f2bf(y[2]); a.w = f2bf(y[3]);
    b.x = f2bf(y[4]); b.y = f2bf(y[5]); b.z = f2bf(y[6]); b.w = f2bf(y[7]);
    *(ushort4*)p = a; *(ushort4*)(p + 4) = b;
}

// ---------------- fp32 -> bf16 elementwise ----------------
__global__ __launch_bounds__(256)
void cvt_f32_bf16(const float* __restrict__ in, u16* __restrict__ out)
{
    const size_t i = ((size_t)blockIdx.x * 256 + threadIdx.x) * 8;
    float y[8];
    load8(in + i, y);
    store8(out + i, y);
}

// ---------------- transpose + convert (generic) ----------------
__global__ __launch_bounds__(256)
void tconv(const float* __restrict__ in, u16* __restrict__ out, int R, int C)
{
    __shared__ float t[32][33];
    const int c0 = blockIdx.x * 32, r0 = blockIdx.y * 32;
    const int tr = threadIdx.x >> 3, c4 = (threadIdx.x & 7) * 4;
    float4 v = *(const float4*)(in + (size_t)(r0 + tr) * C + c0 + c4);
    t[tr][c4] = v.x; t[tr][c4 + 1] = v.y; t[tr][c4 + 2] = v.z; t[tr][c4 + 3] = v.w;
    __syncthreads();
    const int oc = tr, r4 = c4;
    ushort4 u;
    u.x = f2bf(t[r4 + 0][oc]); u.y = f2bf(t[r4 + 1][oc]);
    u.z = f2bf(t[r4 + 2][oc]); u.w = f2bf(t[r4 + 3][oc]);
    *(ushort4*)(out + (size_t)(c0 + oc) * R + r0 + r4) = u;
}

// ---------------- batched 512x512 weight prep -> tail ----------------
// slots [t0^T, t1^T, t2^T, t3 PLAIN, s0^T, s1^T, s2^T, s3^T]
__global__ __launch_bounds__(256)
void tconv8(const float* __restrict__ t_w, const float* __restrict__ s_w,
            u16* __restrict__ out)
{
    __shared__ float t[32][33];
    const int z = blockIdx.z;
    const float* in = (z < 4) ? (t_w + (size_t)z * DD_) : (s_w + (size_t)(z - 4) * DD_);
    u16* o = out + (size_t)z * DD_;
    const int c0 = blockIdx.x * 32, r0 = blockIdx.y * 32;
    const int tr = threadIdx.x >> 3, c4 = (threadIdx.x & 7) * 4;
    float4 v = *(const float4*)(in + (size_t)(r0 + tr) * 512 + c0 + c4);
    if (z == 3) {   // plain convert-copy
        ushort4 u;
        u.x = f2bf(v.x); u.y = f2bf(v.y); u.z = f2bf(v.z); u.w = f2bf(v.w);
        *(ushort4*)(o + (size_t)(r0 + tr) * 512 + c0 + c4) = u;
        return;
    }
    t[tr][c4] = v.x; t[tr][c4 + 1] = v.y; t[tr][c4 + 2] = v.z; t[tr][c4 + 3] = v.w;
    __syncthreads();
    const int oc = tr, r4 = c4;
    ushort4 u;
    u.x = f2bf(t[r4 + 0][oc]); u.y = f2bf(t[r4 + 1][oc]);
    u.z = f2bf(t[r4 + 2][oc]); u.w = f2bf(t[r4 + 3][oc]);
    *(ushort4*)(o + (size_t)(c0 + oc) * 512 + r0 + r4) = u;
}

// ---------------- fused bias: fb[j] = s_b[j] + dot(WTs[j][:], t_b3) ----------------
__global__ __launch_bounds__(256)
void fbias_k(const u16* __restrict__ WTs, const float* __restrict__ tb3,
             const float* __restrict__ sb, float* __restrict__ fb)
{
    const int j = blockIdx.x * 256 + threadIdx.x;   // 0..1535
    const u16* row = WTs + (size_t)j * 512;
    float acc = sb[j];
    for (int k = 0; k < 512; k += 8) {
        float y[8], t[8];
        load8(row + k, y);
        load8(tb3 + k, t);
        acc += y[0]*t[0] + y[1]*t[1] + y[2]*t[2] + y[3]*t[3]
             + y[4]*t[4] + y[5]*t[5] + y[6]*t[6] + y[7]*t[7];
    }
    fb[j] = acc;
}

// ======== 128^2 GEMM (verified rounds 6-10): single-buffer 32 KB,
// XOR bank-deswizzle (both-sides), XCD-chunked grid swizzle ========
#define GEMM_PRE()                                                              \
    const int tid = threadIdx.x;                                                \
    const int w = tid >> 6, l = tid & 63;                                       \
    const int wr = w >> 1, wc = w & 1;                                          \
    const unsigned gx = gridDim.x;                                              \
    const unsigned nwg = gx * gridDim.y;                                        \
    unsigned f = blockIdx.y * gx + blockIdx.x;                                  \
    f = (f & 7) * (nwg >> 3) + (f >> 3);                                        \
    const int lrow = l >> 3;                                                    \
    const int swz8 = (((l & 7) ^ lrow) << 3);                                   \
    const int fr16 = l & 15;                                                    \
    const int kq = l >> 4;

#define GEMM_COMPUTE()                                                          \
    _Pragma("unroll")                                                           \
    for (int kk = 0; kk < 2; ++kk) {                                            \
        const int sw = ((((kk << 2) | kq)) ^ (fr16 & 7)) << 3;                  \
        bf16x8 af[4], bfr[4];                                                   \
        _Pragma("unroll")                                                       \
        for (int i = 0; i < 4; ++i)                                             \
            af[i] = *(bf16x8*)&As[(wr * 64 + i * 16 + fr16) * 64 + sw];         \
        _Pragma("unroll")                                                       \
        for (int j = 0; j < 4; ++j)                                             \
            bfr[j] = *(bf16x8*)&Bs[(wc * 64 + j * 16 + fr16) * 64 + sw];        \
        _Pragma("unroll")                                                       \
        for (int i = 0; i < 4; ++i)                                             \
            _Pragma("unroll")                                                   \
            for (int j = 0; j < 4; ++j)                                         \
                acc[i][j] = __builtin_amdgcn_mfma_f32_16x16x32_bf16(af[i], bfr[j], acc[i][j], 0, 0, 0); \
    }

// ACT: 0 = bias, 1 = bias+leaky, 2 = no-bias
template<int ACT, bool ACC, typename TC>
__global__ __launch_bounds__(256)
void gemm2(const u16* __restrict__ A, const u16* __restrict__ WT,
           const float* __restrict__ bias, TC* __restrict__ C,
           int K, int lda, int ldwt, int ldc)
{
    __shared__ u16 As[128 * 64];
    __shared__ u16 Bs[128 * 64];
    GEMM_PRE();
    const int row0 = (int)(f / gx) * 128, col0 = (int)(f % gx) * 128;
    f32x4 acc[4][4] = {};

    for (int kt = 0; kt < K; kt += 64) {
#pragma unroll
        for (int j = 0; j < 4; ++j) {
            const int line = w * 32 + j * 8;
            const u16* asrc = A  + (size_t)(row0 + line + lrow) * lda  + kt + swz8;
            const u16* bsrc = WT + (size_t)(col0 + line + lrow) * ldwt + kt + swz8;
            __builtin_amdgcn_global_load_lds((glb_u32*)asrc, (lds_u32*)&As[line * 64], 16, 0, 0);
            __builtin_amdgcn_global_load_lds((glb_u32*)bsrc, (lds_u32*)&Bs[line * 64], 16, 0, 0);
        }
        __syncthreads();
        GEMM_COMPUTE();
        __syncthreads();
    }
    const int crow = kq * 4;
#pragma unroll
    for (int i = 0; i < 4; ++i)
#pragma unroll
        for (int j = 0; j < 4; ++j) {
            const int col = col0 + wc * 64 + j * 16 + fr16;
            const float bv = (ACC || ACT == 2) ? 0.f : bias[col];
#pragma unroll
            for (int e = 0; e < 4; ++e) {
                const size_t r = (size_t)(row0 + wr * 64 + i * 16 + crow + e);
                TC* cp = &C[r * (size_t)ldc + col];
                float v = acc[i][j][e] + bv;
                if (ACC) v += cvt_ld(*cp);
                if (ACT == 1) v = (v >= 0.f) ? v : NEG_ * v;
                cvt_st(cp, v);
            }
        }
}

// ================= gemm3 v3: 256x256, BK=32, dbuf 64 KB -> 2 blocks/CU =================
// 512 thr = 8 waves (2x4), per-wave 128x64, 32 MFMA/K-tile. Stage = 4 gloads
// (each 8 KB, lane-linear dest); gate = counted vmcnt(4). BK=32 bank swizzle:
// k-chunk ^= (line>>1)&3, pre-applied on the global source, XOR'd on the read.
template<int ACT, typename TC>
__global__ __launch_bounds__(512)
void gemm3(const u16* __restrict__ A, const u16* __restrict__ WT,
           const float* __restrict__ bias,
           TC* __restrict__ p0, TC* __restrict__ p1, TC* __restrict__ p2,
           int K, int lda, int ldwt, int ldc, int pgshift)
{
    __shared__ u16 lds[32768];   // 64 KB: [buf][A 8192 | ...] A at 0, B at 16384
    const int tid = threadIdx.x;
    const int w = tid >> 6, l = tid & 63;
    const int wr = w >> 2, wc = w & 3;
    const unsigned gx = gridDim.x;
    const unsigned nwg = gx * gridDim.y;
    unsigned f = blockIdx.y * gx + blockIdx.x;
    f = (f & 7) * (nwg >> 3) + (f >> 3);
    const int row0 = (int)(f / gx) * 256, colg0 = (int)(f % gx) * 256;
    const int fr16 = l & 15;
    const int kq = l >> 4;
    const int kc = ((kq ^ ((fr16 >> 1) & 3)) << 3);   // lane's de-swizzled k-chunk (elems)

    f32x4 acc[8][4] = {};
    const int NT = K >> 5;

    auto stage = [&](int buf, int kt) {
        u16* Ad = lds + buf * 8192;
        u16* Bd = lds + 16384 + buf * 8192;
        const int sk = (((l & 3) ^ ((l >> 3) & 3)) << 3);   // pre-swizzled source chunk
#pragma unroll
        for (int part = 0; part < 2; ++part) {
            const int lineb = part * 128 + w * 16;           // wave-uniform dest line
            const int line  = lineb + (l >> 2);
            const u16* asrc = A  + (size_t)(row0  + line) * lda  + kt + sk;
            const u16* bsrc = WT + (size_t)(colg0 + line) * ldwt + kt + sk;
            __builtin_amdgcn_global_load_lds((glb_u32*)asrc, (lds_u32*)&Ad[lineb * 32], 16, 0, 0);
            __builtin_amdgcn_global_load_lds((glb_u32*)bsrc, (lds_u32*)&Bd[lineb * 32], 16, 0, 0);
        }
    };

    stage(0, 0);
    for (int t = 0; t < NT; ++t) {
        const int cur = t & 1;
        if (t + 1 < NT) {
            stage(cur ^ 1, (t + 1) << 5);
            asm volatile("s_waitcnt vmcnt(4)" ::: "memory");   // prev tile's 4 landed
        } else {
            asm volatile("s_waitcnt vmcnt(0)" ::: "memory");
        }
        __builtin_amdgcn_s_barrier();                          // buf[cur] published
        const u16* Ab = lds + cur * 8192;
        const u16* Bb = lds + 16384 + cur * 8192;
        bf16x8 bq[4];
#pragma unroll
        for (int j = 0; j < 4; ++j)
            bq[j] = *(bf16x8*)&Bb[(wc * 64 + j * 16 + fr16) * 32 + kc];
#pragma unroll
        for (int ih = 0; ih < 2; ++ih) {
            bf16x8 af[4];
#pragma unroll
            for (int i = 0; i < 4; ++i)
                af[i] = *(bf16x8*)&Ab[(wr * 128 + (ih * 4 + i) * 16 + fr16) * 32 + kc];
            __builtin_amdgcn_s_setprio(1);
#pragma unroll
            for (int i = 0; i < 4; ++i)
#pragma unroll
                for (int j = 0; j < 4; ++j)
                    acc[ih * 4 + i][j] = __builtin_amdgcn_mfma_f32_16x16x32_bf16(
                        af[i], bq[j], acc[ih * 4 + i][j], 0, 0, 0);
            __builtin_amdgcn_s_setprio(0);
        }
        asm volatile("s_waitcnt lgkmcnt(0)" ::: "memory");
        __builtin_amdgcn_sched_barrier(0);
        __builtin_amdgcn_s_barrier();                          // all reads of buf[cur] done
    }
    // epilogue
    const int crow = kq * 4;
#pragma unroll
    for (int i = 0; i < 8; ++i)
#pragma unroll
        for (int j = 0; j < 4; ++j) {
            const int colg = colg0 + wc * 64 + j * 16 + fr16;
            TC* Cb = (((unsigned)colg >> pgshift) == 0) ? p0
                   : (((unsigned)colg >> pgshift) == 1) ? p1 : p2;
            const int col = colg & ((1 << pgshift) - 1);
            const float bv = bias[colg];
#pragma unroll
            for (int e = 0; e < 4; ++e) {
                const size_t r = (size_t)(row0 + wr * 128 + i * 16 + crow + e);
                float v = acc[i][j][e] + bv;
                if (ACT == 1) v = (v >= 0.f) ? v : NEG_ * v;
                cvt_st(&Cb[r * (size_t)ldc + col], v);
            }
        }
}

// ---------------- MFMA attention (rounds 4-10, verified, unchanged) ----------------
__global__ __launch_bounds__(384)
void attn_mfma(const u16* __restrict__ q, const u16* __restrict__ kbuf,
               const u16* __restrict__ vbuf, const float* __restrict__ mask,
               u16* __restrict__ out, int time_axis)
{
    __shared__ __align__(16) u16 Ks[96][72];
    __shared__ __align__(16) u16 VT[64][104];
    __shared__ __align__(16) u16 Ps[96][104];
    const int g = blockIdx.x;
    const int h = g & 7;
    const int bs = g >> 3;
    const int b = bs / 96, st = bs % 96;
    const size_t base   = time_axis ? ((size_t)(b * 96 + st) * 96) : ((size_t)b * 9216 + st);
    const size_t stride = time_axis ? 1 : 96;
    const int tid = threadIdx.x;
    const int w = tid / 64, l = tid & 63;
    const int fr = l & 15, fk = (l >> 4) * 8;

    for (int task = tid; task < 96 * 8; task += 384) {
        const int r = task >> 3, c = task & 7;
        *(uint4*)&Ks[r][c * 8] =
            *(const uint4*)(kbuf + (base + (size_t)r * stride) * 512 + h * 64 + c * 8);
    }
    for (int task = tid; task < 96 * 8; task += 384) {
        const int r = task >> 3, c = task & 7;
        uint4 dv = *(const uint4*)(vbuf + (base + (size_t)r * stride) * 512 + h * 64 + c * 8);
        const u16* e = (const u16*)&dv;
#pragma unroll
        for (int j = 0; j < 8; ++j) VT[c * 8 + j][r] = e[j];
    }
    const u16* qp = q + (base + (size_t)(16 * w + fr) * stride) * 512 + h * 64;
    bf16x8 aq0 = *(const bf16x8*)(qp + fk);
    bf16x8 aq1 = *(const bf16x8*)(qp + 32 + fk);
    __syncthreads();

    f32x4 s[6] = {};
#pragma unroll
    for (int fc = 0; fc < 6; ++fc) {
        bf16x8 b0 = *(const bf16x8*)&Ks[fc * 16 + fr][fk];
        bf16x8 b1 = *(const bf16x8*)&Ks[fc * 16 + fr][32 + fk];
        s[fc] = __builtin_amdgcn_mfma_f32_16x16x32_bf16(aq0, b0, s[fc], 0, 0, 0);
        s[fc] = __builtin_amdgcn_mfma_f32_16x16x32_bf16(aq1, b1, s[fc], 0, 0, 0);
    }
    float mrow[4], lrow[4];
#pragma unroll
    for (int e = 0; e < 4; ++e) {
        float mx = s[0][e];
#pragma unroll
        for (int fc = 1; fc < 6; ++fc) mx = fmaxf(mx, s[fc][e]);
#pragma unroll
        for (int off = 1; off < 16; off <<= 1) mx = fmaxf(mx, __shfl_xor(mx, off));
        mrow[e] = mx * 0.125f;
        lrow[e] = 0.f;
    }
    const int e0 = (l >> 4) * 4;
#pragma unroll
    for (int fc = 0; fc < 6; ++fc) {
#pragma unroll
        for (int e = 0; e < 4; ++e) {
            const float p = __expf(fmaf(s[fc][e], 0.125f, -mrow[e]));
            lrow[e] += p;
            Ps[16 * w + e0 + e][fc * 16 + fr] = f2bf(p);
        }
    }
#pragma unroll
    for (int e = 0; e < 4; ++e)
#pragma unroll
        for (int off = 1; off < 16; off <<= 1) lrow[e] += __shfl_xor(lrow[e], off);

    __syncthreads();

    f32x4 oacc[4] = {};
#pragma unroll
    for (int ks = 0; ks < 3; ++ks) {
        bf16x8 ap = *(const bf16x8*)&Ps[16 * w + fr][ks * 32 + fk];
#pragma unroll
        for (int j = 0; j < 4; ++j) {
            bf16x8 bv = *(const bf16x8*)&VT[j * 16 + fr][ks * 32 + fk];
            oacc[j] = __builtin_amdgcn_mfma_f32_16x16x32_bf16(ap, bv, oacc[j], 0, 0, 0);
        }
    }
    float mk[4];
#pragma unroll
    for (int e = 0; e < 4; ++e) {
        const size_t qrow = base + (size_t)(16 * w + e0 + e) * stride;
        mk[e] = mask[qrow] / lrow[e];
    }
#pragma unroll
    for (int j = 0; j < 4; ++j)
#pragma unroll
        for (int e = 0; e < 4; ++e) {
            const size_t qrow = base + (size_t)(16 * w + e0 + e) * stride;
            out[qrow * 512 + h * 64 + j * 16 + fr] = f2bf(oacc[j][e] * mk[e]);
        }
}

// ---------------- residual add + LayerNorm (one wave per row of 512) ----------------
template<typename TA, typename TB, typename TO>
__global__ __launch_bounds__(64)
void add_ln(const TA* __restrict__ a, const TB* __restrict__ bsrc,
            const float* __restrict__ g, const float* __restrict__ beta,
            TO* __restrict__ out)
{
    const size_t row = blockIdx.x;
    const int lane = threadIdx.x;
    float ya[8], yb[8], y[8];
    load8(a + row * D_ + lane * 8, ya);
    load8(bsrc + row * D_ + lane * 8, yb);
    float sum = 0.f, sq = 0.f;
#pragma unroll
    for (int i = 0; i < 8; ++i) { y[i] = ya[i] + yb[i]; sum += y[i]; sq += y[i] * y[i]; }
#pragma unroll
    for (int off = 32; off >= 1; off >>= 1) {
        sum += __shfl_xor(sum, off);
        sq  += __shfl_xor(sq, off);
    }
    const float mean = sum * (1.f / D_);
    const float var  = sq * (1.f / D_) - mean * mean;
    const float rstd = rsqrtf(var + EPS_);
    const float* gp = g + lane * 8;
    const float* bp = beta + lane * 8;
    float o[8];
#pragma unroll
    for (int i = 0; i < 8; ++i) o[i] = (y[i] - mean) * rstd * gp[i] + bp[i];
    store8(out + row * D_ + lane * 8, o);
}

extern "C" void kernel_launch(void* const* d_in, const int* in_sizes, int n_in,
                              void* d_out, int out_size, void* d_ws, size_t ws_size,
                              hipStream_t stream)
{
    const float* x     = (const float*)d_in[0];
    const float* mask  = (const float*)d_in[1];
    const float* t_w   = (const float*)d_in[2];
    const float* t_b   = (const float*)d_in[3];
    const float* s_w   = (const float*)d_in[4];
    const float* s_b   = (const float*)d_in[5];
    const float* fc_w1 = (const float*)d_in[6];
    const float* fc_b1 = (const float*)d_in[7];
    const float* fc_w2 = (const float*)d_in[8];
    const float* fc_b2 = (const float*)d_in[9];
    const float* ln1_g = (const float*)d_in[10];
    const float* ln1_b = (const float*)d_in[11];
    const float* ln2_g = (const float*)d_in[12];
    const float* ln2_b = (const float*)d_in[13];

    const size_t PG = (size_t)NROWS * 512;
    const size_t WTC = (size_t)2048 * 512 * 2;    // tail (4 MB): 8xDD slots or fc WTs
    if (ws_size < (PG * 3 + WTC) * sizeof(u16)) return;
    u16* O0   = (u16*)d_out;                      // d_out pages (scratch until final LN)
    u16* O1   = O0 + PG;
    u16* WS0  = (u16*)d_ws;
    u16* WS1  = WS0 + PG;
    u16* WS2  = WS1 + PG;
    u16* TAIL = WS0 + 3 * PG;

    const dim3 gblk(256);
    const dim3 qkv3grid(6, NROWS / 256);          // 864 blocks
    const dim3 ss3grid(2, NROWS / 256);           // 288 blocks
    const dim3 h3grid(8, 72);                     // 576 blocks (M=18432, N=2048)

    // x -> bf16 (WS2 = xb, persists through LN1)
    cvt_f32_bf16<<<dim3((unsigned)(PG / 2048)), gblk, 0, stream>>>(x, WS2);
    // weight prep: slots [t0^T,t1^T,t2^T, t3 PLAIN, s0^T,s1^T,s2^T,s3^T]
    tconv8<<<dim3(16, 16, 8), gblk, 0, stream>>>(t_w, s_w, TAIL);
    // time QKV: q->O0, k->WS0, v->WS1 (reads slots 0-2)
    gemm3<0, u16><<<qkv3grid, dim3(512), 0, stream>>>(
        WS2, TAIL, t_b, O0, WS0, WS1, 512, 512, 512, 512, 9);
    // fused weights: WTf[1536][512] = WTs_{0..2} @ t_w3(plain) -> slots 0-2 (dead after qkv)
    gemm2<2, false, u16><<<dim3(4, 12), gblk, 0, stream>>>(
        TAIL + (size_t)4 * DD_, TAIL + (size_t)3 * DD_, nullptr, TAIL, 512, 512, 512, 512);
    // fused bias -> fp32[1536] at slot-3 bytes
    float* fb = (float*)(TAIL + (size_t)3 * DD_);
    fbias_k<<<dim3(6), gblk, 0, stream>>>(TAIL + (size_t)4 * DD_, t_b + 3 * 512, s_b, fb);
    // time attention: (O0,WS0,WS1) -> O0
    attn_mfma<<<dim3(B_ * H_ * 96), dim3(384), 0, stream>>>(O0, WS0, WS1, mask, O0, 1);
    // space QKV directly from time-attn output (tt GEMM fused away)
    gemm3<0, u16><<<qkv3grid, dim3(512), 0, stream>>>(
        O0, TAIL, fb, O1, WS0, WS1, 512, 512, 512, 512, 9);
    // space attention: (O1,WS0,WS1) -> O0
    attn_mfma<<<dim3(B_ * H_ * 96), dim3(384), 0, stream>>>(O1, WS0, WS1, mask, O0, 0);
    // ss projection: O0 @ s_w3 -> O1 (slot 7) — now gemm3 (288 blocks)
    gemm3<0, u16><<<ss3grid, dim3(512), 0, stream>>>(
        O0, TAIL + (size_t)7 * DD_, s_b + 3 * 512, O1, O1, O1, 512, 512, 512, 512, 30);
    // LN1: x1 = LN(xb + ss) -> WS2 in-place
    add_ln<u16, u16, u16><<<dim3(NROWS), dim3(64), 0, stream>>>(WS2, O1, ln1_g, ln1_b, WS2);
    // fc WTs -> tail (all slots dead now)
    u16* WT1f = TAIL;                             // fc_w1^T (2048 x 512)
    u16* WT2f = TAIL + (size_t)2048 * 512;        // fc_w2^T (512 x 2048)
    tconv<<<dim3(64, 16), gblk, 0, stream>>>(fc_w1, WT1f, 512, 2048);
    tconv<<<dim3(16, 64), gblk, 0, stream>>>(fc_w2, WT2f, 2048, 512);
    // ---- FFN row-split: per half, h fills d_out (2048-wide), single-pass ff -> WS1 ----
    for (int r = 0; r < 2; ++r) {
        const size_t off = (size_t)r * 18432;
        gemm3<1, u16><<<h3grid, dim3(512), 0, stream>>>(
            WS2 + off * 512, WT1f, fc_b1, O0, O0, O0, 512, 512, 512, 2048, 30);
        gemm2<0, false, u16><<<dim3(4, 144), gblk, 0, stream>>>(
            O0, WT2f, fc_b2, WS1 + off * 512, 2048, 2048, 2048, 512);
    }
    // LN2: out = LN(x1 + ff) -> fp32 d_out (sources WS2/WS1 in d_ws only)
    add_ln<u16, u16, float><<<dim3(NROWS), dim3(64), 0, stream>>>(
        WS2, WS1, ln2_g, ln2_b, (float*)d_out);
}

// Round 12
// 551.618 us; speedup vs baseline: 1.0483x; 1.0483x over previous
//
#include <hip/hip_runtime.h>
#include <hip/hip_bf16.h>

#define B_ 4
#define S_ 96
#define T_ 96
#define D_ 512
#define H_ 8
#define FF_ 2048
#define NROWS (B_*S_*T_)   // 36864
#define EPS_ 1e-5f
#define NEG_ 0.01f
#define DD_ (512*512)

typedef unsigned short u16;   // bf16 bits
typedef __attribute__((ext_vector_type(8))) short bf16x8;
typedef __attribute__((ext_vector_type(4))) float f32x4;
typedef __attribute__((address_space(1))) const unsigned glb_u32;
typedef __attribute__((address_space(3))) unsigned lds_u32;

__device__ __forceinline__ float bf(u16 u) { return __uint_as_float(((unsigned)u) << 16); }
__device__ __forceinline__ u16 f2bf(float f) {
    __hip_bfloat16 h = __float2bfloat16(f);
    return *reinterpret_cast<u16*>(&h);
}
__device__ __forceinline__ float blo(unsigned v) { return __uint_as_float(v << 16); }
__device__ __forceinline__ float bhi(unsigned v) { return __uint_as_float(v & 0xffff0000u); }

__device__ __forceinline__ float cvt_ld(float x) { return x; }
__device__ __forceinline__ float cvt_ld(u16 x)  { return bf(x); }
__device__ __forceinline__ void cvt_st(float* p, float v) { *p = v; }
__device__ __forceinline__ void cvt_st(u16* p, float v)   { *p = f2bf(v); }

__device__ __forceinline__ void load8(const float* p, float* y) {
    float4 a = *(const float4*)p, b = *(const float4*)(p + 4);
    y[0]=a.x; y[1]=a.y; y[2]=a.z; y[3]=a.w; y[4]=b.x; y[5]=b.y; y[6]=b.z; y[7]=b.w;
}
__device__ __forceinline__ void load8(const u16* p, float* y) {
    uint4 u = *(const uint4*)p;
    y[0]=blo(u.x); y[1]=bhi(u.x); y[2]=blo(u.y); y[3]=bhi(u.y);
    y[4]=blo(u.z); y[5]=bhi(u.z); y[6]=blo(u.w); y[7]=bhi(u.w);
}
__device__ __forceinline__ void store8(float* p, const float* y) {
    *(float4*)p       = make_float4(y[0], y[1], y[2], y[3]);
    *(float4*)(p + 4) = make_float4(y[4], y[5], y[6], y[7]);
}
__device__ __forceinline__ void store8(u16* p, const float* y) {
    ushort4 a, b;
    a.x = f2bf(y[0]); a.y = f2bf(y[1]); a.z = f2bf(y[2]); a.w = f2bf(y[3]);
    b.x = f2bf(y[4]); b.y = f2bf(y[5]); b.z = f2bf(y[6]); b.w = f2bf(y[7]);
    *(ushort4*)p = a; *(ushort4*)(p + 4) = b;
}

// ---------------- fp32 -> bf16 elementwise (grid-stride) ----------------
__global__ __launch_bounds__(256)
void cvt_f32_bf16(const float* __restrict__ in, u16* __restrict__ out, long n8)
{
    for (long i = (long)blockIdx.x * 256 + threadIdx.x; i < n8; i += (long)gridDim.x * 256) {
        float y[8];
        load8(in + i * 8, y);
        store8(out + i * 8, y);
    }
}

// ---------------- transpose + convert (generic) ----------------
__global__ __launch_bounds__(256)
void tconv(const float* __restrict__ in, u16* __restrict__ out, int R, int C)
{
    __shared__ float t[32][33];
    const int c0 = blockIdx.x * 32, r0 = blockIdx.y * 32;
    const int tr = threadIdx.x >> 3, c4 = (threadIdx.x & 7) * 4;
    float4 v = *(const float4*)(in + (size_t)(r0 + tr) * C + c0 + c4);
    t[tr][c4] = v.x; t[tr][c4 + 1] = v.y; t[tr][c4 + 2] = v.z; t[tr][c4 + 3] = v.w;
    __syncthreads();
    const int oc = tr, r4 = c4;
    ushort4 u;
    u.x = f2bf(t[r4 + 0][oc]); u.y = f2bf(t[r4 + 1][oc]);
    u.z = f2bf(t[r4 + 2][oc]); u.w = f2bf(t[r4 + 3][oc]);
    *(ushort4*)(out + (size_t)(c0 + oc) * R + r0 + r4) = u;
}

// ---------------- batched 512x512 weight prep -> tail ----------------
// slots [t0^T, t1^T, t2^T, t3 PLAIN, s0^T, s1^T, s2^T, s3^T]
__global__ __launch_bounds__(256)
void tconv8(const float* __restrict__ t_w, const float* __restrict__ s_w,
            u16* __restrict__ out)
{
    __shared__ float t[32][33];
    const int z = blockIdx.z;
    const float* in = (z < 4) ? (t_w + (size_t)z * DD_) : (s_w + (size_t)(z - 4) * DD_);
    u16* o = out + (size_t)z * DD_;
    const int c0 = blockIdx.x * 32, r0 = blockIdx.y * 32;
    const int tr = threadIdx.x >> 3, c4 = (threadIdx.x & 7) * 4;
    float4 v = *(const float4*)(in + (size_t)(r0 + tr) * 512 + c0 + c4);
    if (z == 3) {   // plain convert-copy
        ushort4 u;
        u.x = f2bf(v.x); u.y = f2bf(v.y); u.z = f2bf(v.z); u.w = f2bf(v.w);
        *(ushort4*)(o + (size_t)(r0 + tr) * 512 + c0 + c4) = u;
        return;
    }
    t[tr][c4] = v.x; t[tr][c4 + 1] = v.y; t[tr][c4 + 2] = v.z; t[tr][c4 + 3] = v.w;
    __syncthreads();
    const int oc = tr, r4 = c4;
    ushort4 u;
    u.x = f2bf(t[r4 + 0][oc]); u.y = f2bf(t[r4 + 1][oc]);
    u.z = f2bf(t[r4 + 2][oc]); u.w = f2bf(t[r4 + 3][oc]);
    *(ushort4*)(o + (size_t)(c0 + oc) * 512 + r0 + r4) = u;
}

// ---------------- fused bias: fb[j] = s_b[j] + dot(WTs[j][:], t_b3) ----------------
__global__ __launch_bounds__(256)
void fbias_k(const u16* __restrict__ WTs, const float* __restrict__ tb3,
             const float* __restrict__ sb, float* __restrict__ fb)
{
    const int j = blockIdx.x * 256 + threadIdx.x;   // 0..1535
    const u16* row = WTs + (size_t)j * 512;
    float acc = sb[j];
    for (int k = 0; k < 512; k += 8) {
        float y[8], t[8];
        load8(row + k, y);
        load8(tb3 + k, t);
        acc += y[0]*t[0] + y[1]*t[1] + y[2]*t[2] + y[3]*t[3]
             + y[4]*t[4] + y[5]*t[5] + y[6]*t[6] + y[7]*t[7];
    }
    fb[j] = acc;
}

// ======== 128^2 GEMM (verified rounds 6-10): single-buffer 32 KB,
// XOR bank-deswizzle (both-sides), XCD-chunked grid swizzle ========
#define GEMM_PRE()                                                              \
    const int tid = threadIdx.x;                                                \
    const int w = tid >> 6, l = tid & 63;                                       \
    const int wr = w >> 1, wc = w & 1;                                          \
    const unsigned gx = gridDim.x;                                              \
    const unsigned nwg = gx * gridDim.y;                                        \
    unsigned f = blockIdx.y * gx + blockIdx.x;                                  \
    f = (f & 7) * (nwg >> 3) + (f >> 3);                                        \
    const int lrow = l >> 3;                                                    \
    const int swz8 = (((l & 7) ^ lrow) << 3);                                   \
    const int fr16 = l & 15;                                                    \
    const int kq = l >> 4;

#define GEMM_COMPUTE()                                                          \
    _Pragma("unroll")                                                           \
    for (int kk = 0; kk < 2; ++kk) {                                            \
        const int sw = ((((kk << 2) | kq)) ^ (fr16 & 7)) << 3;                  \
        bf16x8 af[4], bfr[4];                                                   \
        _Pragma("unroll")                                                       \
        for (int i = 0; i < 4; ++i)                                             \
            af[i] = *(bf16x8*)&As[(wr * 64 + i * 16 + fr16) * 64 + sw];         \
        _Pragma("unroll")                                                       \
        for (int j = 0; j < 4; ++j)                                             \
            bfr[j] = *(bf16x8*)&Bs[(wc * 64 + j * 16 + fr16) * 64 + sw];        \
        _Pragma("unroll")                                                       \
        for (int i = 0; i < 4; ++i)                                             \
            _Pragma("unroll")                                                   \
            for (int j = 0; j < 4; ++j)                                         \
                acc[i][j] = __builtin_amdgcn_mfma_f32_16x16x32_bf16(af[i], bfr[j], acc[i][j], 0, 0, 0); \
    }

// ACT: 0 = bias, 1 = bias+leaky, 2 = no-bias
template<int ACT, bool ACC, typename TC>
__global__ __launch_bounds__(256)
void gemm2(const u16* __restrict__ A, const u16* __restrict__ WT,
           const float* __restrict__ bias, TC* __restrict__ C,
           int K, int lda, int ldwt, int ldc)
{
    __shared__ u16 As[128 * 64];
    __shared__ u16 Bs[128 * 64];
    GEMM_PRE();
    const int row0 = (int)(f / gx) * 128, col0 = (int)(f % gx) * 128;
    f32x4 acc[4][4] = {};

    for (int kt = 0; kt < K; kt += 64) {
#pragma unroll
        for (int j = 0; j < 4; ++j) {
            const int line = w * 32 + j * 8;
            const u16* asrc = A  + (size_t)(row0 + line + lrow) * lda  + kt + swz8;
            const u16* bsrc = WT + (size_t)(col0 + line + lrow) * ldwt + kt + swz8;
            __builtin_amdgcn_global_load_lds((glb_u32*)asrc, (lds_u32*)&As[line * 64], 16, 0, 0);
            __builtin_amdgcn_global_load_lds((glb_u32*)bsrc, (lds_u32*)&Bs[line * 64], 16, 0, 0);
        }
        __syncthreads();
        GEMM_COMPUTE();
        __syncthreads();
    }
    const int crow = kq * 4;
#pragma unroll
    for (int i = 0; i < 4; ++i)
#pragma unroll
        for (int j = 0; j < 4; ++j) {
            const int col = col0 + wc * 64 + j * 16 + fr16;
            const float bv = (ACC || ACT == 2) ? 0.f : bias[col];
#pragma unroll
            for (int e = 0; e < 4; ++e) {
                const size_t r = (size_t)(row0 + wr * 64 + i * 16 + crow + e);
                TC* cp = &C[r * (size_t)ldc + col];
                float v = acc[i][j][e] + bv;
                if (ACC) v += cvt_ld(*cp);
                if (ACT == 1) v = (v >= 0.f) ? v : NEG_ * v;
                cvt_st(cp, v);
            }
        }
}

// ================= gemm3 (round-10 verified config): 256x256, BK=64,
// dbuf 128 KB + counted vmcnt(8) + 4-phase interior =================
template<int ACT, typename TC>
__global__ __launch_bounds__(512)
void gemm3(const u16* __restrict__ A, const u16* __restrict__ WT,
           const float* __restrict__ bias,
           TC* __restrict__ p0, TC* __restrict__ p1, TC* __restrict__ p2,
           int K, int lda, int ldwt, int ldc, int pgshift)
{
    __shared__ u16 lds[65536];   // 128 KB
    const int tid = threadIdx.x;
    const int w = tid >> 6, l = tid & 63;
    const int wr = w >> 2, wc = w & 3;
    const unsigned gx = gridDim.x;
    const unsigned nwg = gx * gridDim.y;
    unsigned f = blockIdx.y * gx + blockIdx.x;
    f = (f & 7) * (nwg >> 3) + (f >> 3);
    const int row0 = (int)(f / gx) * 256, colg0 = (int)(f % gx) * 256;
    const int lrow = l >> 3;
    const int swz8 = (((l & 7) ^ lrow) << 3);
    const int fr16 = l & 15;
    const int kq = l >> 4;

    f32x4 acc[8][4] = {};
    const int NT = K >> 6;

    auto stage = [&](int buf, int kt) {
        u16* Ad = lds + buf * 16384;
        u16* Bd = lds + 32768 + buf * 16384;
#pragma unroll
        for (int j = 0; j < 4; ++j) {
            const int lineb = j * 64 + w * 8;
            const int srow = lineb + lrow;
            const u16* asrc = A  + (size_t)(row0  + srow) * lda  + kt + swz8;
            const u16* bsrc = WT + (size_t)(colg0 + srow) * ldwt + kt + swz8;
            __builtin_amdgcn_global_load_lds((glb_u32*)asrc, (lds_u32*)&Ad[lineb * 64], 16, 0, 0);
            __builtin_amdgcn_global_load_lds((glb_u32*)bsrc, (lds_u32*)&Bd[lineb * 64], 16, 0, 0);
        }
    };

    stage(0, 0);
    for (int t = 0; t < NT; ++t) {
        const int cur = t & 1;
        if (t + 1 < NT) {
            stage(cur ^ 1, (t + 1) << 6);
            asm volatile("s_waitcnt vmcnt(8)" ::: "memory");
        } else {
            asm volatile("s_waitcnt vmcnt(0)" ::: "memory");
        }
        __builtin_amdgcn_s_barrier();                     // gate: buf[cur] published
        const u16* Ab = lds + cur * 16384;
        const u16* Bb = lds + 32768 + cur * 16384;
        bf16x8 bq[4];
#pragma unroll
        for (int p = 0; p < 4; ++p) {
            const int kk = p >> 1, ih = p & 1;
            const int sw = ((((kk << 2) | kq)) ^ (fr16 & 7)) << 3;
            if (ih == 0) {
#pragma unroll
                for (int j = 0; j < 4; ++j)
                    bq[j] = *(bf16x8*)&Bb[(wc * 64 + j * 16 + fr16) * 64 + sw];
            }
            bf16x8 af[4];
#pragma unroll
            for (int i = 0; i < 4; ++i)
                af[i] = *(bf16x8*)&Ab[(wr * 128 + (ih * 4 + i) * 16 + fr16) * 64 + sw];
            __builtin_amdgcn_s_barrier();                 // phase alignment
            __builtin_amdgcn_s_setprio(1);
#pragma unroll
            for (int i = 0; i < 4; ++i)
#pragma unroll
                for (int j = 0; j < 4; ++j)
                    acc[ih * 4 + i][j] = __builtin_amdgcn_mfma_f32_16x16x32_bf16(
                        af[i], bq[j], acc[ih * 4 + i][j], 0, 0, 0);
            __builtin_amdgcn_s_setprio(0);
        }
    }
    const int crow = kq * 4;
#pragma unroll
    for (int i = 0; i < 8; ++i)
#pragma unroll
        for (int j = 0; j < 4; ++j) {
            const int colg = colg0 + wc * 64 + j * 16 + fr16;
            TC* Cb = (((unsigned)colg >> pgshift) == 0) ? p0
                   : (((unsigned)colg >> pgshift) == 1) ? p1 : p2;
            const int col = colg & ((1 << pgshift) - 1);
            const float bv = bias[colg];
#pragma unroll
            for (int e = 0; e < 4; ++e) {
                const size_t r = (size_t)(row0 + wr * 128 + i * 16 + crow + e);
                float v = acc[i][j][e] + bv;
                if (ACT == 1) v = (v >= 0.f) ? v : NEG_ * v;
                cvt_st(&Cb[r * (size_t)ldc + col], v);
            }
        }
}

// ---------------- MFMA attention (rounds 4-11, verified, unchanged) ----------------
__global__ __launch_bounds__(384)
void attn_mfma(const u16* __restrict__ q, const u16* __restrict__ kbuf,
               const u16* __restrict__ vbuf, const float* __restrict__ mask,
               u16* __restrict__ out, int time_axis)
{
    __shared__ __align__(16) u16 Ks[96][72];
    __shared__ __align__(16) u16 VT[64][104];
    __shared__ __align__(16) u16 Ps[96][104];
    const int g = blockIdx.x;
    const int h = g & 7;
    const int bs = g >> 3;
    const int b = bs / 96, st = bs % 96;
    const size_t base   = time_axis ? ((size_t)(b * 96 + st) * 96) : ((size_t)b * 9216 + st);
    const size_t stride = time_axis ? 1 : 96;
    const int tid = threadIdx.x;
    const int w = tid / 64, l = tid & 63;
    const int fr = l & 15, fk = (l >> 4) * 8;

    for (int task = tid; task < 96 * 8; task += 384) {
        const int r = task >> 3, c = task & 7;
        *(uint4*)&Ks[r][c * 8] =
            *(const uint4*)(kbuf + (base + (size_t)r * stride) * 512 + h * 64 + c * 8);
    }
    for (int task = tid; task < 96 * 8; task += 384) {
        const int r = task >> 3, c = task & 7;
        uint4 dv = *(const uint4*)(vbuf + (base + (size_t)r * stride) * 512 + h * 64 + c * 8);
        const u16* e = (const u16*)&dv;
#pragma unroll
        for (int j = 0; j < 8; ++j) VT[c * 8 + j][r] = e[j];
    }
    const u16* qp = q + (base + (size_t)(16 * w + fr) * stride) * 512 + h * 64;
    bf16x8 aq0 = *(const bf16x8*)(qp + fk);
    bf16x8 aq1 = *(const bf16x8*)(qp + 32 + fk);
    __syncthreads();

    f32x4 s[6] = {};
#pragma unroll
    for (int fc = 0; fc < 6; ++fc) {
        bf16x8 b0 = *(const bf16x8*)&Ks[fc * 16 + fr][fk];
        bf16x8 b1 = *(const bf16x8*)&Ks[fc * 16 + fr][32 + fk];
        s[fc] = __builtin_amdgcn_mfma_f32_16x16x32_bf16(aq0, b0, s[fc], 0, 0, 0);
        s[fc] = __builtin_amdgcn_mfma_f32_16x16x32_bf16(aq1, b1, s[fc], 0, 0, 0);
    }
    float mrow[4], lrow[4];
#pragma unroll
    for (int e = 0; e < 4; ++e) {
        float mx = s[0][e];
#pragma unroll
        for (int fc = 1; fc < 6; ++fc) mx = fmaxf(mx, s[fc][e]);
#pragma unroll
        for (int off = 1; off < 16; off <<= 1) mx = fmaxf(mx, __shfl_xor(mx, off));
        mrow[e] = mx * 0.125f;
        lrow[e] = 0.f;
    }
    const int e0 = (l >> 4) * 4;
#pragma unroll
    for (int fc = 0; fc < 6; ++fc) {
#pragma unroll
        for (int e = 0; e < 4; ++e) {
            const float p = __expf(fmaf(s[fc][e], 0.125f, -mrow[e]));
            lrow[e] += p;
            Ps[16 * w + e0 + e][fc * 16 + fr] = f2bf(p);
        }
    }
#pragma unroll
    for (int e = 0; e < 4; ++e)
#pragma unroll
        for (int off = 1; off < 16; off <<= 1) lrow[e] += __shfl_xor(lrow[e], off);

    __syncthreads();

    f32x4 oacc[4] = {};
#pragma unroll
    for (int ks = 0; ks < 3; ++ks) {
        bf16x8 ap = *(const bf16x8*)&Ps[16 * w + fr][ks * 32 + fk];
#pragma unroll
        for (int j = 0; j < 4; ++j) {
            bf16x8 bv = *(const bf16x8*)&VT[j * 16 + fr][ks * 32 + fk];
            oacc[j] = __builtin_amdgcn_mfma_f32_16x16x32_bf16(ap, bv, oacc[j], 0, 0, 0);
        }
    }
    float mk[4];
#pragma unroll
    for (int e = 0; e < 4; ++e) {
        const size_t qrow = base + (size_t)(16 * w + e0 + e) * stride;
        mk[e] = mask[qrow] / lrow[e];
    }
#pragma unroll
    for (int j = 0; j < 4; ++j)
#pragma unroll
        for (int e = 0; e < 4; ++e) {
            const size_t qrow = base + (size_t)(16 * w + e0 + e) * stride;
            out[qrow * 512 + h * 64 + j * 16 + fr] = f2bf(oacc[j][e] * mk[e]);
        }
}

// ---------------- residual add + LayerNorm: 4 rows/block, one wave per row ----------------
template<typename TA, typename TB, typename TO>
__global__ __launch_bounds__(256)
void add_ln(const TA* __restrict__ a, const TB* __restrict__ bsrc,
            const float* __restrict__ g, const float* __restrict__ beta,
            TO* __restrict__ out)
{
    const size_t row = (size_t)blockIdx.x * 4 + (threadIdx.x >> 6);
    const int lane = threadIdx.x & 63;
    float ya[8], yb[8], y[8];
    load8(a + row * D_ + lane * 8, ya);
    load8(bsrc + row * D_ + lane * 8, yb);
    float sum = 0.f, sq = 0.f;
#pragma unroll
    for (int i = 0; i < 8; ++i) { y[i] = ya[i] + yb[i]; sum += y[i]; sq += y[i] * y[i]; }
#pragma unroll
    for (int off = 32; off >= 1; off >>= 1) {
        sum += __shfl_xor(sum, off);
        sq  += __shfl_xor(sq, off);
    }
    const float mean = sum * (1.f / D_);
    const float var  = sq * (1.f / D_) - mean * mean;
    const float rstd = rsqrtf(var + EPS_);
    const float* gp = g + lane * 8;
    const float* bp = beta + lane * 8;
    float o[8];
#pragma unroll
    for (int i = 0; i < 8; ++i) o[i] = (y[i] - mean) * rstd * gp[i] + bp[i];
    store8(out + row * D_ + lane * 8, o);
}

extern "C" void kernel_launch(void* const* d_in, const int* in_sizes, int n_in,
                              void* d_out, int out_size, void* d_ws, size_t ws_size,
                              hipStream_t stream)
{
    const float* x     = (const float*)d_in[0];
    const float* mask  = (const float*)d_in[1];
    const float* t_w   = (const float*)d_in[2];
    const float* t_b   = (const float*)d_in[3];
    const float* s_w   = (const float*)d_in[4];
    const float* s_b   = (const float*)d_in[5];
    const float* fc_w1 = (const float*)d_in[6];
    const float* fc_b1 = (const float*)d_in[7];
    const float* fc_w2 = (const float*)d_in[8];
    const float* fc_b2 = (const float*)d_in[9];
    const float* ln1_g = (const float*)d_in[10];
    const float* ln1_b = (const float*)d_in[11];
    const float* ln2_g = (const float*)d_in[12];
    const float* ln2_b = (const float*)d_in[13];

    const size_t PG = (size_t)NROWS * 512;
    const size_t WTC = (size_t)2048 * 512 * 2;    // tail (4 MB): 8xDD slots or fc WTs
    if (ws_size < (PG * 3 + WTC) * sizeof(u16)) return;
    u16* O0   = (u16*)d_out;                      // d_out pages (scratch until final LN)
    u16* O1   = O0 + PG;
    u16* WS0  = (u16*)d_ws;
    u16* WS1  = WS0 + PG;
    u16* WS2  = WS1 + PG;
    u16* TAIL = WS0 + 3 * PG;

    const dim3 gblk(256);
    const dim3 g512(4, NROWS / 128);
    const dim3 qkv3grid(6, NROWS / 256);          // 864 blocks
    const dim3 h3grid(8, 72);                     // 576 blocks (M=18432, N=2048)
    const dim3 lngrid(NROWS / 4);

    // x -> bf16 (WS2 = xb, persists through LN1)
    cvt_f32_bf16<<<dim3(2048), gblk, 0, stream>>>(x, WS2, (long)(PG / 8));
    // weight prep: slots [t0^T,t1^T,t2^T, t3 PLAIN, s0^T,s1^T,s2^T,s3^T]
    tconv8<<<dim3(16, 16, 8), gblk, 0, stream>>>(t_w, s_w, TAIL);
    // time QKV: q->O0, k->WS0, v->WS1 (reads slots 0-2)
    gemm3<0, u16><<<qkv3grid, dim3(512), 0, stream>>>(
        WS2, TAIL, t_b, O0, WS0, WS1, 512, 512, 512, 512, 9);
    // fused weights: WTf[1536][512] = WTs_{0..2} @ t_w3(plain) -> slots 0-2 (dead after qkv)
    gemm2<2, false, u16><<<dim3(4, 12), gblk, 0, stream>>>(
        TAIL + (size_t)4 * DD_, TAIL + (size_t)3 * DD_, nullptr, TAIL, 512, 512, 512, 512);
    // fused bias -> fp32[1536] at slot-3 bytes
    float* fb = (float*)(TAIL + (size_t)3 * DD_);
    fbias_k<<<dim3(6), gblk, 0, stream>>>(TAIL + (size_t)4 * DD_, t_b + 3 * 512, s_b, fb);
    // time attention: (O0,WS0,WS1) -> O0
    attn_mfma<<<dim3(B_ * H_ * 96), dim3(384), 0, stream>>>(O0, WS0, WS1, mask, O0, 1);
    // space QKV directly from time-attn output (tt GEMM fused away)
    gemm3<0, u16><<<qkv3grid, dim3(512), 0, stream>>>(
        O0, TAIL, fb, O1, WS0, WS1, 512, 512, 512, 512, 9);
    // space attention: (O1,WS0,WS1) -> O0
    attn_mfma<<<dim3(B_ * H_ * 96), dim3(384), 0, stream>>>(O1, WS0, WS1, mask, O0, 0);
    // ss projection: O0 @ s_w3 -> O1 (slot 7)
    gemm2<0, false, u16><<<g512, gblk, 0, stream>>>(
        O0, TAIL + (size_t)7 * DD_, s_b + 3 * 512, O1, 512, 512, 512, 512);
    // LN1: x1 = LN(xb + ss) -> WS2 in-place
    add_ln<u16, u16, u16><<<lngrid, gblk, 0, stream>>>(WS2, O1, ln1_g, ln1_b, WS2);
    // fc WTs -> tail (all slots dead now)
    u16* WT1f = TAIL;                             // fc_w1^T (2048 x 512)
    u16* WT2f = TAIL + (size_t)2048 * 512;        // fc_w2^T (512 x 2048)
    tconv<<<dim3(64, 16), gblk, 0, stream>>>(fc_w1, WT1f, 512, 2048);
    tconv<<<dim3(16, 64), gblk, 0, stream>>>(fc_w2, WT2f, 2048, 512);
    // ---- FFN row-split: per half, h fills d_out (2048-wide), single-pass ff -> WS1 ----
    for (int r = 0; r < 2; ++r) {
        const size_t off = (size_t)r * 18432;
        gemm3<1, u16><<<h3grid, dim3(512), 0, stream>>>(
            WS2 + off * 512, WT1f, fc_b1, O0, O0, O0, 512, 512, 512, 2048, 30);
        gemm2<0, false, u16><<<dim3(4, 144), gblk, 0, stream>>>(
            O0, WT2f, fc_b2, WS1 + off * 512, 2048, 2048, 2048, 512);
    }
    // LN2: out = LN(x1 + ff) -> fp32 d_out (sources WS2/WS1 in d_ws only)
    add_ln<u16, u16, float><<<lngrid, gblk, 0, stream>>>(
        WS2, WS1, ln2_g, ln2_b, (float*)d_out);
}

// Round 13
// 503.462 us; speedup vs baseline: 1.1486x; 1.0956x over previous
//
#include <hip/hip_runtime.h>
#include <hip/hip_bf16.h>

#define B_ 4
#define S_ 96
#define T_ 96
#define D_ 512
#define H_ 8
#define FF_ 2048
#define NROWS (B_*S_*T_)   // 36864
#define EPS_ 1e-5f
#define NEG_ 0.01f
#define DD_ (512*512)

typedef unsigned short u16;   // bf16 bits
typedef __attribute__((ext_vector_type(8))) short bf16x8;
typedef __attribute__((ext_vector_type(4))) float f32x4;
typedef __attribute__((address_space(1))) const unsigned glb_u32;
typedef __attribute__((address_space(3))) unsigned lds_u32;

__device__ __forceinline__ float bf(u16 u) { return __uint_as_float(((unsigned)u) << 16); }
__device__ __forceinline__ u16 f2bf(float f) {
    __hip_bfloat16 h = __float2bfloat16(f);
    return *reinterpret_cast<u16*>(&h);
}
__device__ __forceinline__ float blo(unsigned v) { return __uint_as_float(v << 16); }
__device__ __forceinline__ float bhi(unsigned v) { return __uint_as_float(v & 0xffff0000u); }

__device__ __forceinline__ float cvt_ld(float x) { return x; }
__device__ __forceinline__ float cvt_ld(u16 x)  { return bf(x); }
__device__ __forceinline__ void cvt_st(float* p, float v) { *p = v; }
__device__ __forceinline__ void cvt_st(u16* p, float v)   { *p = f2bf(v); }

__device__ __forceinline__ void load8(const float* p, float* y) {
    float4 a = *(const float4*)p, b = *(const float4*)(p + 4);
    y[0]=a.x; y[1]=a.y; y[2]=a.z; y[3]=a.w; y[4]=b.x; y[5]=b.y; y[6]=b.z; y[7]=b.w;
}
__device__ __forceinline__ void load8(const u16* p, float* y) {
    uint4 u = *(const uint4*)p;
    y[0]=blo(u.x); y[1]=bhi(u.x); y[2]=blo(u.y); y[3]=bhi(u.y);
    y[4]=blo(u.z); y[5]=bhi(u.z); y[6]=blo(u.w); y[7]=bhi(u.w);
}
__device__ __forceinline__ void store8(float* p, const float* y) {
    *(float4*)p       = make_float4(y[0], y[1], y[2], y[3]);
    *(float4*)(p + 4) = make_float4(y[4], y[5], y[6], y[7]);
}
__device__ __forceinline__ void store8(u16* p, const float* y) {
    ushort4 a, b;
    a.x = f2bf(y[0]); a.y = f2bf(y[1]); a.z = f2bf(y[2]); a.w = f2bf(y[3]);
    b.x = f2bf(y[4]); b.y = f2bf(y[5]); b.z = f2bf(y[6]); b.w = f2bf(y[7]);
    *(ushort4*)p = a; *(ushort4*)(p + 4) = b;
}

// ---------------- fp32 -> bf16 elementwise (grid-stride) ----------------
__global__ __launch_bounds__(256)
void cvt_f32_bf16(const float* __restrict__ in, u16* __restrict__ out, long n8)
{
    for (long i = (long)blockIdx.x * 256 + threadIdx.x; i < n8; i += (long)gridDim.x * 256) {
        float y[8];
        load8(in + i * 8, y);
        store8(out + i * 8, y);
    }
}

// ---------------- transpose + convert (generic) ----------------
__global__ __launch_bounds__(256)
void tconv(const float* __restrict__ in, u16* __restrict__ out, int R, int C)
{
    __shared__ float t[32][33];
    const int c0 = blockIdx.x * 32, r0 = blockIdx.y * 32;
    const int tr = threadIdx.x >> 3, c4 = (threadIdx.x & 7) * 4;
    float4 v = *(const float4*)(in + (size_t)(r0 + tr) * C + c0 + c4);
    t[tr][c4] = v.x; t[tr][c4 + 1] = v.y; t[tr][c4 + 2] = v.z; t[tr][c4 + 3] = v.w;
    __syncthreads();
    const int oc = tr, r4 = c4;
    ushort4 u;
    u.x = f2bf(t[r4 + 0][oc]); u.y = f2bf(t[r4 + 1][oc]);
    u.z = f2bf(t[r4 + 2][oc]); u.w = f2bf(t[r4 + 3][oc]);
    *(ushort4*)(out + (size_t)(c0 + oc) * R + r0 + r4) = u;
}

// ---------------- batched 512x512 weight prep -> tail ----------------
// slots [t0^T, t1^T, t2^T, t3 PLAIN, s0^T, s1^T, s2^T, s3^T]
__global__ __launch_bounds__(256)
void tconv8(const float* __restrict__ t_w, const float* __restrict__ s_w,
            u16* __restrict__ out)
{
    __shared__ float t[32][33];
    const int z = blockIdx.z;
    const float* in = (z < 4) ? (t_w + (size_t)z * DD_) : (s_w + (size_t)(z - 4) * DD_);
    u16* o = out + (size_t)z * DD_;
    const int c0 = blockIdx.x * 32, r0 = blockIdx.y * 32;
    const int tr = threadIdx.x >> 3, c4 = (threadIdx.x & 7) * 4;
    float4 v = *(const float4*)(in + (size_t)(r0 + tr) * 512 + c0 + c4);
    if (z == 3) {   // plain convert-copy
        ushort4 u;
        u.x = f2bf(v.x); u.y = f2bf(v.y); u.z = f2bf(v.z); u.w = f2bf(v.w);
        *(ushort4*)(o + (size_t)(r0 + tr) * 512 + c0 + c4) = u;
        return;
    }
    t[tr][c4] = v.x; t[tr][c4 + 1] = v.y; t[tr][c4 + 2] = v.z; t[tr][c4 + 3] = v.w;
    __syncthreads();
    const int oc = tr, r4 = c4;
    ushort4 u;
    u.x = f2bf(t[r4 + 0][oc]); u.y = f2bf(t[r4 + 1][oc]);
    u.z = f2bf(t[r4 + 2][oc]); u.w = f2bf(t[r4 + 3][oc]);
    *(ushort4*)(o + (size_t)(c0 + oc) * 512 + r0 + r4) = u;
}

// ---------------- fused bias: fb[j] = s_b[j] + dot(WTs[j][:], t_b3) ----------------
__global__ __launch_bounds__(256)
void fbias_k(const u16* __restrict__ WTs, const float* __restrict__ tb3,
             const float* __restrict__ sb, float* __restrict__ fb)
{
    const int j = blockIdx.x * 256 + threadIdx.x;   // 0..1535
    const u16* row = WTs + (size_t)j * 512;
    float acc = sb[j];
    for (int k = 0; k < 512; k += 8) {
        float y[8], t[8];
        load8(row + k, y);
        load8(tb3 + k, t);
        acc += y[0]*t[0] + y[1]*t[1] + y[2]*t[2] + y[3]*t[3]
             + y[4]*t[4] + y[5]*t[5] + y[6]*t[6] + y[7]*t[7];
    }
    fb[j] = acc;
}

// ======== 128^2 GEMM (verified rounds 6-12): single-buffer 32 KB,
// XOR bank-deswizzle (both-sides), XCD-chunked grid swizzle ========
#define GEMM_PRE()                                                              \
    const int tid = threadIdx.x;                                                \
    const int w = tid >> 6, l = tid & 63;                                       \
    const int wr = w >> 1, wc = w & 1;                                          \
    const unsigned gx = gridDim.x;                                              \
    const unsigned nwg = gx * gridDim.y;                                        \
    unsigned f = blockIdx.y * gx + blockIdx.x;                                  \
    f = (f & 7) * (nwg >> 3) + (f >> 3);                                        \
    const int lrow = l >> 3;                                                    \
    const int swz8 = (((l & 7) ^ lrow) << 3);                                   \
    const int fr16 = l & 15;                                                    \
    const int kq = l >> 4;

#define GEMM_COMPUTE()                                                          \
    _Pragma("unroll")                                                           \
    for (int kk = 0; kk < 2; ++kk) {                                            \
        const int sw = ((((kk << 2) | kq)) ^ (fr16 & 7)) << 3;                  \
        bf16x8 af[4], bfr[4];                                                   \
        _Pragma("unroll")                                                       \
        for (int i = 0; i < 4; ++i)                                             \
            af[i] = *(bf16x8*)&As[(wr * 64 + i * 16 + fr16) * 64 + sw];         \
        _Pragma("unroll")                                                       \
        for (int j = 0; j < 4; ++j)                                             \
            bfr[j] = *(bf16x8*)&Bs[(wc * 64 + j * 16 + fr16) * 64 + sw];        \
        _Pragma("unroll")                                                       \
        for (int i = 0; i < 4; ++i)                                             \
            _Pragma("unroll")                                                   \
            for (int j = 0; j < 4; ++j)                                         \
                acc[i][j] = __builtin_amdgcn_mfma_f32_16x16x32_bf16(af[i], bfr[j], acc[i][j], 0, 0, 0); \
    }

// ACT: 0 = bias, 1 = bias+leaky, 2 = no-bias
template<int ACT, bool ACC, typename TC>
__global__ __launch_bounds__(256)
void gemm2(const u16* __restrict__ A, const u16* __restrict__ WT,
           const float* __restrict__ bias, TC* __restrict__ C,
           int K, int lda, int ldwt, int ldc)
{
    __shared__ u16 As[128 * 64];
    __shared__ u16 Bs[128 * 64];
    GEMM_PRE();
    const int row0 = (int)(f / gx) * 128, col0 = (int)(f % gx) * 128;
    f32x4 acc[4][4] = {};

    for (int kt = 0; kt < K; kt += 64) {
#pragma unroll
        for (int j = 0; j < 4; ++j) {
            const int line = w * 32 + j * 8;
            const u16* asrc = A  + (size_t)(row0 + line + lrow) * lda  + kt + swz8;
            const u16* bsrc = WT + (size_t)(col0 + line + lrow) * ldwt + kt + swz8;
            __builtin_amdgcn_global_load_lds((glb_u32*)asrc, (lds_u32*)&As[line * 64], 16, 0, 0);
            __builtin_amdgcn_global_load_lds((glb_u32*)bsrc, (lds_u32*)&Bs[line * 64], 16, 0, 0);
        }
        __syncthreads();
        GEMM_COMPUTE();
        __syncthreads();
    }
    const int crow = kq * 4;
#pragma unroll
    for (int i = 0; i < 4; ++i)
#pragma unroll
        for (int j = 0; j < 4; ++j) {
            const int col = col0 + wc * 64 + j * 16 + fr16;
            const float bv = (ACC || ACT == 2) ? 0.f : bias[col];
#pragma unroll
            for (int e = 0; e < 4; ++e) {
                const size_t r = (size_t)(row0 + wr * 64 + i * 16 + crow + e);
                TC* cp = &C[r * (size_t)ldc + col];
                float v = acc[i][j][e] + bv;
                if (ACC) v += cvt_ld(*cp);
                if (ACT == 1) v = (v >= 0.f) ? v : NEG_ * v;
                cvt_st(cp, v);
            }
        }
}

// ================= gemm3 v4: 192x128 tile, BK=64, dbuf 80 KB -> 2 blocks/CU =================
// 512 thr = 8 waves (4 row-groups x 2 col-groups); per-wave 48x64 (acc 3x4).
// Schedule IDENTICAL to verified r12: stage whole next tile (5 gloads), counted
// vmcnt(5), gate barrier, 2 kk-phases each {7 ds_read_b128; barrier; setprio; 12 MFMA}.
// Same 8-chunk XOR swizzle (positions step 64 lines so line&7 == l>>3 per lane).
// Grids exact multiples of 256: qkv 2304, h 1536, ss 768 -> zero tail quantization.
template<int ACT, typename TC>
__global__ __launch_bounds__(512)
void gemm3(const u16* __restrict__ A, const u16* __restrict__ WT,
           const float* __restrict__ bias,
           TC* __restrict__ p0, TC* __restrict__ p1, TC* __restrict__ p2,
           int K, int lda, int ldwt, int ldc, int pgshift)
{
    __shared__ u16 lds[40960];   // 80 KB: A dbuf 2x12288 @0, B dbuf 2x8192 @24576
    const int tid = threadIdx.x;
    const int w = tid >> 6, l = tid & 63;
    const int wr = w >> 1, wc = w & 1;
    const unsigned gx = gridDim.x;
    const unsigned nwg = gx * gridDim.y;
    unsigned f = blockIdx.y * gx + blockIdx.x;
    f = (f & 7) * (nwg >> 3) + (f >> 3);
    const int row0 = (int)(f / gx) * 192, colg0 = (int)(f % gx) * 128;
    const int lrow = l >> 3;
    const int swz8 = (((l & 7) ^ lrow) << 3);
    const int fr16 = l & 15;
    const int kq = l >> 4;

    f32x4 acc[3][4] = {};
    const int NT = K >> 6;

    auto stage = [&](int buf, int kt) {
        u16* Ad = lds + buf * 12288;
        u16* Bd = lds + 24576 + buf * 8192;
#pragma unroll
        for (int P = 0; P < 3; ++P) {                 // A: 192 lines in 3 positions
            const int lineb = P * 64 + w * 8;         // wave-uniform dest line
            const u16* asrc = A + (size_t)(row0 + lineb + lrow) * lda + kt + swz8;
            __builtin_amdgcn_global_load_lds((glb_u32*)asrc, (lds_u32*)&Ad[lineb * 64], 16, 0, 0);
        }
#pragma unroll
        for (int P = 0; P < 2; ++P) {                 // B: 128 lines in 2 positions
            const int lineb = P * 64 + w * 8;
            const u16* bsrc = WT + (size_t)(colg0 + lineb + lrow) * ldwt + kt + swz8;
            __builtin_amdgcn_global_load_lds((glb_u32*)bsrc, (lds_u32*)&Bd[lineb * 64], 16, 0, 0);
        }
    };

    stage(0, 0);
    for (int t = 0; t < NT; ++t) {
        const int cur = t & 1;
        if (t + 1 < NT) {
            stage(cur ^ 1, (t + 1) << 6);
            asm volatile("s_waitcnt vmcnt(5)" ::: "memory");   // prev tile's 5 landed
        } else {
            asm volatile("s_waitcnt vmcnt(0)" ::: "memory");
        }
        __builtin_amdgcn_s_barrier();                          // gate: buf[cur] published
        const u16* Ab = lds + cur * 12288;
        const u16* Bb = lds + 24576 + cur * 8192;
#pragma unroll
        for (int kk = 0; kk < 2; ++kk) {
            const int sw = ((((kk << 2) | kq)) ^ (fr16 & 7)) << 3;
            bf16x8 bq[4], af[3];
#pragma unroll
            for (int j = 0; j < 4; ++j)
                bq[j] = *(bf16x8*)&Bb[(wc * 64 + j * 16 + fr16) * 64 + sw];
#pragma unroll
            for (int i = 0; i < 3; ++i)
                af[i] = *(bf16x8*)&Ab[(wr * 48 + i * 16 + fr16) * 64 + sw];
            __builtin_amdgcn_s_barrier();                      // phase alignment
            __builtin_amdgcn_s_setprio(1);
#pragma unroll
            for (int i = 0; i < 3; ++i)
#pragma unroll
                for (int j = 0; j < 4; ++j)
                    acc[i][j] = __builtin_amdgcn_mfma_f32_16x16x32_bf16(
                        af[i], bq[j], acc[i][j], 0, 0, 0);
            __builtin_amdgcn_s_setprio(0);
        }
    }
    // epilogue
    const int crow = kq * 4;
#pragma unroll
    for (int i = 0; i < 3; ++i)
#pragma unroll
        for (int j = 0; j < 4; ++j) {
            const int colg = colg0 + wc * 64 + j * 16 + fr16;
            TC* Cb = (((unsigned)colg >> pgshift) == 0) ? p0
                   : (((unsigned)colg >> pgshift) == 1) ? p1 : p2;
            const int col = colg & ((1 << pgshift) - 1);
            const float bv = bias[colg];
#pragma unroll
            for (int e = 0; e < 4; ++e) {
                const size_t r = (size_t)(row0 + wr * 48 + i * 16 + crow + e);
                float v = acc[i][j][e] + bv;
                if (ACT == 1) v = (v >= 0.f) ? v : NEG_ * v;
                cvt_st(&Cb[r * (size_t)ldc + col], v);
            }
        }
}

// ---------------- MFMA attention (rounds 4-12, verified, unchanged) ----------------
__global__ __launch_bounds__(384)
void attn_mfma(const u16* __restrict__ q, const u16* __restrict__ kbuf,
               const u16* __restrict__ vbuf, const float* __restrict__ mask,
               u16* __restrict__ out, int time_axis)
{
    __shared__ __align__(16) u16 Ks[96][72];
    __shared__ __align__(16) u16 VT[64][104];
    __shared__ __align__(16) u16 Ps[96][104];
    const int g = blockIdx.x;
    const int h = g & 7;
    const int bs = g >> 3;
    const int b = bs / 96, st = bs % 96;
    const size_t base   = time_axis ? ((size_t)(b * 96 + st) * 96) : ((size_t)b * 9216 + st);
    const size_t stride = time_axis ? 1 : 96;
    const int tid = threadIdx.x;
    const int w = tid / 64, l = tid & 63;
    const int fr = l & 15, fk = (l >> 4) * 8;

    for (int task = tid; task < 96 * 8; task += 384) {
        const int r = task >> 3, c = task & 7;
        *(uint4*)&Ks[r][c * 8] =
            *(const uint4*)(kbuf + (base + (size_t)r * stride) * 512 + h * 64 + c * 8);
    }
    for (int task = tid; task < 96 * 8; task += 384) {
        const int r = task >> 3, c = task & 7;
        uint4 dv = *(const uint4*)(vbuf + (base + (size_t)r * stride) * 512 + h * 64 + c * 8);
        const u16* e = (const u16*)&dv;
#pragma unroll
        for (int j = 0; j < 8; ++j) VT[c * 8 + j][r] = e[j];
    }
    const u16* qp = q + (base + (size_t)(16 * w + fr) * stride) * 512 + h * 64;
    bf16x8 aq0 = *(const bf16x8*)(qp + fk);
    bf16x8 aq1 = *(const bf16x8*)(qp + 32 + fk);
    __syncthreads();

    f32x4 s[6] = {};
#pragma unroll
    for (int fc = 0; fc < 6; ++fc) {
        bf16x8 b0 = *(const bf16x8*)&Ks[fc * 16 + fr][fk];
        bf16x8 b1 = *(const bf16x8*)&Ks[fc * 16 + fr][32 + fk];
        s[fc] = __builtin_amdgcn_mfma_f32_16x16x32_bf16(aq0, b0, s[fc], 0, 0, 0);
        s[fc] = __builtin_amdgcn_mfma_f32_16x16x32_bf16(aq1, b1, s[fc], 0, 0, 0);
    }
    float mrow[4], lrow[4];
#pragma unroll
    for (int e = 0; e < 4; ++e) {
        float mx = s[0][e];
#pragma unroll
        for (int fc = 1; fc < 6; ++fc) mx = fmaxf(mx, s[fc][e]);
#pragma unroll
        for (int off = 1; off < 16; off <<= 1) mx = fmaxf(mx, __shfl_xor(mx, off));
        mrow[e] = mx * 0.125f;
        lrow[e] = 0.f;
    }
    const int e0 = (l >> 4) * 4;
#pragma unroll
    for (int fc = 0; fc < 6; ++fc) {
#pragma unroll
        for (int e = 0; e < 4; ++e) {
            const float p = __expf(fmaf(s[fc][e], 0.125f, -mrow[e]));
            lrow[e] += p;
            Ps[16 * w + e0 + e][fc * 16 + fr] = f2bf(p);
        }
    }
#pragma unroll
    for (int e = 0; e < 4; ++e)
#pragma unroll
        for (int off = 1; off < 16; off <<= 1) lrow[e] += __shfl_xor(lrow[e], off);

    __syncthreads();

    f32x4 oacc[4] = {};
#pragma unroll
    for (int ks = 0; ks < 3; ++ks) {
        bf16x8 ap = *(const bf16x8*)&Ps[16 * w + fr][ks * 32 + fk];
#pragma unroll
        for (int j = 0; j < 4; ++j) {
            bf16x8 bv = *(const bf16x8*)&VT[j * 16 + fr][ks * 32 + fk];
            oacc[j] = __builtin_amdgcn_mfma_f32_16x16x32_bf16(ap, bv, oacc[j], 0, 0, 0);
        }
    }
    float mk[4];
#pragma unroll
    for (int e = 0; e < 4; ++e) {
        const size_t qrow = base + (size_t)(16 * w + e0 + e) * stride;
        mk[e] = mask[qrow] / lrow[e];
    }
#pragma unroll
    for (int j = 0; j < 4; ++j)
#pragma unroll
        for (int e = 0; e < 4; ++e) {
            const size_t qrow = base + (size_t)(16 * w + e0 + e) * stride;
            out[qrow * 512 + h * 64 + j * 16 + fr] = f2bf(oacc[j][e] * mk[e]);
        }
}

// ---------------- residual add + LayerNorm: 4 rows/block, one wave per row ----------------
template<typename TA, typename TB, typename TO>
__global__ __launch_bounds__(256)
void add_ln(const TA* __restrict__ a, const TB* __restrict__ bsrc,
            const float* __restrict__ g, const float* __restrict__ beta,
            TO* __restrict__ out)
{
    const size_t row = (size_t)blockIdx.x * 4 + (threadIdx.x >> 6);
    const int lane = threadIdx.x & 63;
    float ya[8], yb[8], y[8];
    load8(a + row * D_ + lane * 8, ya);
    load8(bsrc + row * D_ + lane * 8, yb);
    float sum = 0.f, sq = 0.f;
#pragma unroll
    for (int i = 0; i < 8; ++i) { y[i] = ya[i] + yb[i]; sum += y[i]; sq += y[i] * y[i]; }
#pragma unroll
    for (int off = 32; off >= 1; off >>= 1) {
        sum += __shfl_xor(sum, off);
        sq  += __shfl_xor(sq, off);
    }
    const float mean = sum * (1.f / D_);
    const float var  = sq * (1.f / D_) - mean * mean;
    const float rstd = rsqrtf(var + EPS_);
    const float* gp = g + lane * 8;
    const float* bp = beta + lane * 8;
    float o[8];
#pragma unroll
    for (int i = 0; i < 8; ++i) o[i] = (y[i] - mean) * rstd * gp[i] + bp[i];
    store8(out + row * D_ + lane * 8, o);
}

extern "C" void kernel_launch(void* const* d_in, const int* in_sizes, int n_in,
                              void* d_out, int out_size, void* d_ws, size_t ws_size,
                              hipStream_t stream)
{
    const float* x     = (const float*)d_in[0];
    const float* mask  = (const float*)d_in[1];
    const float* t_w   = (const float*)d_in[2];
    const float* t_b   = (const float*)d_in[3];
    const float* s_w   = (const float*)d_in[4];
    const float* s_b   = (const float*)d_in[5];
    const float* fc_w1 = (const float*)d_in[6];
    const float* fc_b1 = (const float*)d_in[7];
    const float* fc_w2 = (const float*)d_in[8];
    const float* fc_b2 = (const float*)d_in[9];
    const float* ln1_g = (const float*)d_in[10];
    const float* ln1_b = (const float*)d_in[11];
    const float* ln2_g = (const float*)d_in[12];
    const float* ln2_b = (const float*)d_in[13];

    const size_t PG = (size_t)NROWS * 512;
    const size_t WTC = (size_t)2048 * 512 * 2;    // tail (4 MB): 8xDD slots or fc WTs
    if (ws_size < (PG * 3 + WTC) * sizeof(u16)) return;
    u16* O0   = (u16*)d_out;                      // d_out pages (scratch until final LN)
    u16* O1   = O0 + PG;
    u16* WS0  = (u16*)d_ws;
    u16* WS1  = WS0 + PG;
    u16* WS2  = WS1 + PG;
    u16* TAIL = WS0 + 3 * PG;

    const dim3 gblk(256);
    const dim3 qkv3grid(12, NROWS / 192);         // 2304 blocks = 9 exact rounds
    const dim3 ss3grid(4, NROWS / 192);           // 768 blocks = 3 exact rounds
    const dim3 h3grid(16, 18432 / 192);           // 1536 blocks = 6 exact rounds
    const dim3 lngrid(NROWS / 4);

    // x -> bf16 (WS2 = xb, persists through LN1)
    cvt_f32_bf16<<<dim3(2048), gblk, 0, stream>>>(x, WS2, (long)(PG / 8));
    // weight prep: slots [t0^T,t1^T,t2^T, t3 PLAIN, s0^T,s1^T,s2^T,s3^T]
    tconv8<<<dim3(16, 16, 8), gblk, 0, stream>>>(t_w, s_w, TAIL);
    // time QKV: q->O0, k->WS0, v->WS1 (reads slots 0-2)
    gemm3<0, u16><<<qkv3grid, dim3(512), 0, stream>>>(
        WS2, TAIL, t_b, O0, WS0, WS1, 512, 512, 512, 512, 9);
    // fused weights: WTf[1536][512] = WTs_{0..2} @ t_w3(plain) -> slots 0-2 (dead after qkv)
    gemm2<2, false, u16><<<dim3(4, 12), gblk, 0, stream>>>(
        TAIL + (size_t)4 * DD_, TAIL + (size_t)3 * DD_, nullptr, TAIL, 512, 512, 512, 512);
    // fused bias -> fp32[1536] at slot-3 bytes
    float* fb = (float*)(TAIL + (size_t)3 * DD_);
    fbias_k<<<dim3(6), gblk, 0, stream>>>(TAIL + (size_t)4 * DD_, t_b + 3 * 512, s_b, fb);
    // time attention: (O0,WS0,WS1) -> O0
    attn_mfma<<<dim3(B_ * H_ * 96), dim3(384), 0, stream>>>(O0, WS0, WS1, mask, O0, 1);
    // space QKV directly from time-attn output (tt GEMM fused away)
    gemm3<0, u16><<<qkv3grid, dim3(512), 0, stream>>>(
        O0, TAIL, fb, O1, WS0, WS1, 512, 512, 512, 512, 9);
    // space attention: (O1,WS0,WS1) -> O0
    attn_mfma<<<dim3(B_ * H_ * 96), dim3(384), 0, stream>>>(O1, WS0, WS1, mask, O0, 0);
    // ss projection: O0 @ s_w3 -> O1 (slot 7)
    gemm3<0, u16><<<ss3grid, dim3(512), 0, stream>>>(
        O0, TAIL + (size_t)7 * DD_, s_b + 3 * 512, O1, O1, O1, 512, 512, 512, 512, 30);
    // LN1: x1 = LN(xb + ss) -> WS2 in-place
    add_ln<u16, u16, u16><<<lngrid, gblk, 0, stream>>>(WS2, O1, ln1_g, ln1_b, WS2);
    // fc WTs -> tail (all slots dead now)
    u16* WT1f = TAIL;                             // fc_w1^T (2048 x 512)
    u16* WT2f = TAIL + (size_t)2048 * 512;        // fc_w2^T (512 x 2048)
    tconv<<<dim3(64, 16), gblk, 0, stream>>>(fc_w1, WT1f, 512, 2048);
    tconv<<<dim3(16, 64), gblk, 0, stream>>>(fc_w2, WT2f, 2048, 512);
    // ---- FFN row-split: per half, h fills d_out (2048-wide), single-pass ff -> WS1 ----
    for (int r = 0; r < 2; ++r) {
        const size_t off = (size_t)r * 18432;
        gemm3<1, u16><<<h3grid, dim3(512), 0, stream>>>(
            WS2 + off * 512, WT1f, fc_b1, O0, O0, O0, 512, 512, 512, 2048, 30);
        gemm2<0, false, u16><<<dim3(4, 144), gblk, 0, stream>>>(
            O0, WT2f, fc_b2, WS1 + off * 512, 2048, 2048, 2048, 512);
    }
    // LN2: out = LN(x1 + ff) -> fp32 d_out (sources WS2/WS1 in d_ws only)
    add_ln<u16, u16, float><<<lngrid, gblk, 0, stream>>>(
        WS2, WS1, ln2_g, ln2_b, (float*)d_out);
}

// Round 14
// 492.173 us; speedup vs baseline: 1.1749x; 1.0229x over previous
//
#include <hip/hip_runtime.h>
#include <hip/hip_bf16.h>

#define B_ 4
#define S_ 96
#define T_ 96
#define D_ 512
#define H_ 8
#define FF_ 2048
#define NROWS (B_*S_*T_)   // 36864
#define EPS_ 1e-5f
#define NEG_ 0.01f
#define DD_ (512*512)

typedef unsigned short u16;   // bf16 bits
typedef __attribute__((ext_vector_type(8))) short bf16x8;
typedef __attribute__((ext_vector_type(4))) float f32x4;
typedef __attribute__((address_space(1))) const unsigned glb_u32;
typedef __attribute__((address_space(3))) unsigned lds_u32;

__device__ __forceinline__ float bf(u16 u) { return __uint_as_float(((unsigned)u) << 16); }
__device__ __forceinline__ u16 f2bf(float f) {
    __hip_bfloat16 h = __float2bfloat16(f);
    return *reinterpret_cast<u16*>(&h);
}
__device__ __forceinline__ float blo(unsigned v) { return __uint_as_float(v << 16); }
__device__ __forceinline__ float bhi(unsigned v) { return __uint_as_float(v & 0xffff0000u); }

__device__ __forceinline__ float cvt_ld(float x) { return x; }
__device__ __forceinline__ float cvt_ld(u16 x)  { return bf(x); }
__device__ __forceinline__ void cvt_st(float* p, float v) { *p = v; }
__device__ __forceinline__ void cvt_st(u16* p, float v)   { *p = f2bf(v); }

__device__ __forceinline__ void load8(const float* p, float* y) {
    float4 a = *(const float4*)p, b = *(const float4*)(p + 4);
    y[0]=a.x; y[1]=a.y; y[2]=a.z; y[3]=a.w; y[4]=b.x; y[5]=b.y; y[6]=b.z; y[7]=b.w;
}
__device__ __forceinline__ void load8(const u16* p, float* y) {
    uint4 u = *(const uint4*)p;
    y[0]=blo(u.x); y[1]=bhi(u.x); y[2]=blo(u.y); y[3]=bhi(u.y);
    y[4]=blo(u.z); y[5]=bhi(u.z); y[6]=blo(u.w); y[7]=bhi(u.w);
}
__device__ __forceinline__ void store8(float* p, const float* y) {
    *(float4*)p       = make_float4(y[0], y[1], y[2], y[3]);
    *(float4*)(p + 4) = make_float4(y[4], y[5], y[6], y[7]);
}
__device__ __forceinline__ void store8(u16* p, const float* y) {
    ushort4 a, b;
    a.x = f2bf(y[0]); a.y = f2bf(y[1]); a.z = f2bf(y[2]); a.w = f2bf(y[3]);
    b.x = f2bf(y[4]); b.y = f2bf(y[5]); b.z = f2bf(y[6]); b.w = f2bf(y[7]);
    *(ushort4*)p = a; *(ushort4*)(p + 4) = b;
}

// ---------------- fp32 -> bf16 elementwise (grid-stride) ----------------
__global__ __launch_bounds__(256)
void cvt_f32_bf16(const float* __restrict__ in, u16* __restrict__ out, long n8)
{
    for (long i = (long)blockIdx.x * 256 + threadIdx.x; i < n8; i += (long)gridDim.x * 256) {
        float y[8];
        load8(in + i * 8, y);
        store8(out + i * 8, y);
    }
}

// ---------------- transpose + convert (generic) ----------------
__global__ __launch_bounds__(256)
void tconv(const float* __restrict__ in, u16* __restrict__ out, int R, int C)
{
    __shared__ float t[32][33];
    const int c0 = blockIdx.x * 32, r0 = blockIdx.y * 32;
    const int tr = threadIdx.x >> 3, c4 = (threadIdx.x & 7) * 4;
    float4 v = *(const float4*)(in + (size_t)(r0 + tr) * C + c0 + c4);
    t[tr][c4] = v.x; t[tr][c4 + 1] = v.y; t[tr][c4 + 2] = v.z; t[tr][c4 + 3] = v.w;
    __syncthreads();
    const int oc = tr, r4 = c4;
    ushort4 u;
    u.x = f2bf(t[r4 + 0][oc]); u.y = f2bf(t[r4 + 1][oc]);
    u.z = f2bf(t[r4 + 2][oc]); u.w = f2bf(t[r4 + 3][oc]);
    *(ushort4*)(out + (size_t)(c0 + oc) * R + r0 + r4) = u;
}

// ---------------- batched 512x512 weight prep -> tail ----------------
// slots [t0^T, t1^T, t2^T, t3 PLAIN, s0^T, s1^T, s2^T, s3^T]
__global__ __launch_bounds__(256)
void tconv8(const float* __restrict__ t_w, const float* __restrict__ s_w,
            u16* __restrict__ out)
{
    __shared__ float t[32][33];
    const int z = blockIdx.z;
    const float* in = (z < 4) ? (t_w + (size_t)z * DD_) : (s_w + (size_t)(z - 4) * DD_);
    u16* o = out + (size_t)z * DD_;
    const int c0 = blockIdx.x * 32, r0 = blockIdx.y * 32;
    const int tr = threadIdx.x >> 3, c4 = (threadIdx.x & 7) * 4;
    float4 v = *(const float4*)(in + (size_t)(r0 + tr) * 512 + c0 + c4);
    if (z == 3) {   // plain convert-copy
        ushort4 u;
        u.x = f2bf(v.x); u.y = f2bf(v.y); u.z = f2bf(v.z); u.w = f2bf(v.w);
        *(ushort4*)(o + (size_t)(r0 + tr) * 512 + c0 + c4) = u;
        return;
    }
    t[tr][c4] = v.x; t[tr][c4 + 1] = v.y; t[tr][c4 + 2] = v.z; t[tr][c4 + 3] = v.w;
    __syncthreads();
    const int oc = tr, r4 = c4;
    ushort4 u;
    u.x = f2bf(t[r4 + 0][oc]); u.y = f2bf(t[r4 + 1][oc]);
    u.z = f2bf(t[r4 + 2][oc]); u.w = f2bf(t[r4 + 3][oc]);
    *(ushort4*)(o + (size_t)(c0 + oc) * 512 + r0 + r4) = u;
}

// ---------------- fused bias: fb[j] = s_b[j] + dot(WTs[j][:], t_b3) ----------------
__global__ __launch_bounds__(256)
void fbias_k(const u16* __restrict__ WTs, const float* __restrict__ tb3,
             const float* __restrict__ sb, float* __restrict__ fb)
{
    const int j = blockIdx.x * 256 + threadIdx.x;   // 0..1535
    const u16* row = WTs + (size_t)j * 512;
    float acc = sb[j];
    for (int k = 0; k < 512; k += 8) {
        float y[8], t[8];
        load8(row + k, y);
        load8(tb3 + k, t);
        acc += y[0]*t[0] + y[1]*t[1] + y[2]*t[2] + y[3]*t[3]
             + y[4]*t[4] + y[5]*t[5] + y[6]*t[6] + y[7]*t[7];
    }
    fb[j] = acc;
}

// ======== 128^2 GEMM (verified rounds 6-13): single-buffer 32 KB,
// XOR bank-deswizzle (both-sides), XCD-chunked grid swizzle ========
#define GEMM_PRE()                                                              \
    const int tid = threadIdx.x;                                                \
    const int w = tid >> 6, l = tid & 63;                                       \
    const int wr = w >> 1, wc = w & 1;                                          \
    const unsigned gx = gridDim.x;                                              \
    const unsigned nwg = gx * gridDim.y;                                        \
    unsigned f = blockIdx.y * gx + blockIdx.x;                                  \
    f = (f & 7) * (nwg >> 3) + (f >> 3);                                        \
    const int lrow = l >> 3;                                                    \
    const int swz8 = (((l & 7) ^ lrow) << 3);                                   \
    const int fr16 = l & 15;                                                    \
    const int kq = l >> 4;

#define GEMM_COMPUTE()                                                          \
    _Pragma("unroll")                                                           \
    for (int kk = 0; kk < 2; ++kk) {                                            \
        const int sw = ((((kk << 2) | kq)) ^ (fr16 & 7)) << 3;                  \
        bf16x8 af[4], bfr[4];                                                   \
        _Pragma("unroll")                                                       \
        for (int i = 0; i < 4; ++i)                                             \
            af[i] = *(bf16x8*)&As[(wr * 64 + i * 16 + fr16) * 64 + sw];         \
        _Pragma("unroll")                                                       \
        for (int j = 0; j < 4; ++j)                                             \
            bfr[j] = *(bf16x8*)&Bs[(wc * 64 + j * 16 + fr16) * 64 + sw];        \
        _Pragma("unroll")                                                       \
        for (int i = 0; i < 4; ++i)                                             \
            _Pragma("unroll")                                                   \
            for (int j = 0; j < 4; ++j)                                         \
                acc[i][j] = __builtin_amdgcn_mfma_f32_16x16x32_bf16(af[i], bfr[j], acc[i][j], 0, 0, 0); \
    }

// ACT: 0 = bias, 1 = bias+leaky, 2 = no-bias
template<int ACT, bool ACC, typename TC>
__global__ __launch_bounds__(256)
void gemm2(const u16* __restrict__ A, const u16* __restrict__ WT,
           const float* __restrict__ bias, TC* __restrict__ C,
           int K, int lda, int ldwt, int ldc)
{
    __shared__ u16 As[128 * 64];
    __shared__ u16 Bs[128 * 64];
    GEMM_PRE();
    const int row0 = (int)(f / gx) * 128, col0 = (int)(f % gx) * 128;
    f32x4 acc[4][4] = {};

    for (int kt = 0; kt < K; kt += 64) {
#pragma unroll
        for (int j = 0; j < 4; ++j) {
            const int line = w * 32 + j * 8;
            const u16* asrc = A  + (size_t)(row0 + line + lrow) * lda  + kt + swz8;
            const u16* bsrc = WT + (size_t)(col0 + line + lrow) * ldwt + kt + swz8;
            __builtin_amdgcn_global_load_lds((glb_u32*)asrc, (lds_u32*)&As[line * 64], 16, 0, 0);
            __builtin_amdgcn_global_load_lds((glb_u32*)bsrc, (lds_u32*)&Bs[line * 64], 16, 0, 0);
        }
        __syncthreads();
        GEMM_COMPUTE();
        __syncthreads();
    }
    const int crow = kq * 4;
#pragma unroll
    for (int i = 0; i < 4; ++i)
#pragma unroll
        for (int j = 0; j < 4; ++j) {
            const int col = col0 + wc * 64 + j * 16 + fr16;
            const float bv = (ACC || ACT == 2) ? 0.f : bias[col];
#pragma unroll
            for (int e = 0; e < 4; ++e) {
                const size_t r = (size_t)(row0 + wr * 64 + i * 16 + crow + e);
                TC* cp = &C[r * (size_t)ldc + col];
                float v = acc[i][j][e] + bv;
                if (ACC) v += cvt_ld(*cp);
                if (ACT == 1) v = (v >= 0.f) ? v : NEG_ * v;
                cvt_st(cp, v);
            }
        }
}

// ================= gemm3 (r13 verified): 192x128 tile, BK=64, dbuf 80 KB, 2 blocks/CU ======
// 512 thr = 8 waves (4 row-groups x 2 col-groups); per-wave 48x64 (acc 3x4).
// Stage whole next tile (5 gloads), counted vmcnt(5), gate barrier, 2 kk-phases
// each {7 ds_read_b128; barrier; setprio; 12 MFMA}. 8-chunk XOR swizzle.
template<int ACT, typename TC>
__global__ __launch_bounds__(512)
void gemm3(const u16* __restrict__ A, const u16* __restrict__ WT,
           const float* __restrict__ bias,
           TC* __restrict__ p0, TC* __restrict__ p1, TC* __restrict__ p2,
           int K, int lda, int ldwt, int ldc, int pgshift)
{
    __shared__ u16 lds[40960];   // 80 KB: A dbuf 2x12288 @0, B dbuf 2x8192 @24576
    const int tid = threadIdx.x;
    const int w = tid >> 6, l = tid & 63;
    const int wr = w >> 1, wc = w & 1;
    const unsigned gx = gridDim.x;
    const unsigned nwg = gx * gridDim.y;
    unsigned f = blockIdx.y * gx + blockIdx.x;
    f = (f & 7) * (nwg >> 3) + (f >> 3);
    const int row0 = (int)(f / gx) * 192, colg0 = (int)(f % gx) * 128;
    const int lrow = l >> 3;
    const int swz8 = (((l & 7) ^ lrow) << 3);
    const int fr16 = l & 15;
    const int kq = l >> 4;

    f32x4 acc[3][4] = {};
    const int NT = K >> 6;

    auto stage = [&](int buf, int kt) {
        u16* Ad = lds + buf * 12288;
        u16* Bd = lds + 24576 + buf * 8192;
#pragma unroll
        for (int P = 0; P < 3; ++P) {                 // A: 192 lines in 3 positions
            const int lineb = P * 64 + w * 8;         // wave-uniform dest line
            const u16* asrc = A + (size_t)(row0 + lineb + lrow) * lda + kt + swz8;
            __builtin_amdgcn_global_load_lds((glb_u32*)asrc, (lds_u32*)&Ad[lineb * 64], 16, 0, 0);
        }
#pragma unroll
        for (int P = 0; P < 2; ++P) {                 // B: 128 lines in 2 positions
            const int lineb = P * 64 + w * 8;
            const u16* bsrc = WT + (size_t)(colg0 + lineb + lrow) * ldwt + kt + swz8;
            __builtin_amdgcn_global_load_lds((glb_u32*)bsrc, (lds_u32*)&Bd[lineb * 64], 16, 0, 0);
        }
    };

    stage(0, 0);
    for (int t = 0; t < NT; ++t) {
        const int cur = t & 1;
        if (t + 1 < NT) {
            stage(cur ^ 1, (t + 1) << 6);
            asm volatile("s_waitcnt vmcnt(5)" ::: "memory");   // prev tile's 5 landed
        } else {
            asm volatile("s_waitcnt vmcnt(0)" ::: "memory");
        }
        __builtin_amdgcn_s_barrier();                          // gate: buf[cur] published
        const u16* Ab = lds + cur * 12288;
        const u16* Bb = lds + 24576 + cur * 8192;
#pragma unroll
        for (int kk = 0; kk < 2; ++kk) {
            const int sw = ((((kk << 2) | kq)) ^ (fr16 & 7)) << 3;
            bf16x8 bq[4], af[3];
#pragma unroll
            for (int j = 0; j < 4; ++j)
                bq[j] = *(bf16x8*)&Bb[(wc * 64 + j * 16 + fr16) * 64 + sw];
#pragma unroll
            for (int i = 0; i < 3; ++i)
                af[i] = *(bf16x8*)&Ab[(wr * 48 + i * 16 + fr16) * 64 + sw];
            __builtin_amdgcn_s_barrier();                      // phase alignment
            __builtin_amdgcn_s_setprio(1);
#pragma unroll
            for (int i = 0; i < 3; ++i)
#pragma unroll
                for (int j = 0; j < 4; ++j)
                    acc[i][j] = __builtin_amdgcn_mfma_f32_16x16x32_bf16(
                        af[i], bq[j], acc[i][j], 0, 0, 0);
            __builtin_amdgcn_s_setprio(0);
        }
    }
    // epilogue
    const int crow = kq * 4;
#pragma unroll
    for (int i = 0; i < 3; ++i)
#pragma unroll
        for (int j = 0; j < 4; ++j) {
            const int colg = colg0 + wc * 64 + j * 16 + fr16;
            TC* Cb = (((unsigned)colg >> pgshift) == 0) ? p0
                   : (((unsigned)colg >> pgshift) == 1) ? p1 : p2;
            const int col = colg & ((1 << pgshift) - 1);
            const float bv = bias[colg];
#pragma unroll
            for (int e = 0; e < 4; ++e) {
                const size_t r = (size_t)(row0 + wr * 48 + i * 16 + crow + e);
                float v = acc[i][j][e] + bv;
                if (ACT == 1) v = (v >= 0.f) ? v : NEG_ * v;
                cvt_st(&Cb[r * (size_t)ldc + col], v);
            }
        }
}

// ---------------- MFMA attention (rounds 4-13, verified, unchanged) ----------------
__global__ __launch_bounds__(384)
void attn_mfma(const u16* __restrict__ q, const u16* __restrict__ kbuf,
               const u16* __restrict__ vbuf, const float* __restrict__ mask,
               u16* __restrict__ out, int time_axis)
{
    __shared__ __align__(16) u16 Ks[96][72];
    __shared__ __align__(16) u16 VT[64][104];
    __shared__ __align__(16) u16 Ps[96][104];
    const int g = blockIdx.x;
    const int h = g & 7;
    const int bs = g >> 3;
    const int b = bs / 96, st = bs % 96;
    const size_t base   = time_axis ? ((size_t)(b * 96 + st) * 96) : ((size_t)b * 9216 + st);
    const size_t stride = time_axis ? 1 : 96;
    const int tid = threadIdx.x;
    const int w = tid / 64, l = tid & 63;
    const int fr = l & 15, fk = (l >> 4) * 8;

    for (int task = tid; task < 96 * 8; task += 384) {
        const int r = task >> 3, c = task & 7;
        *(uint4*)&Ks[r][c * 8] =
            *(const uint4*)(kbuf + (base + (size_t)r * stride) * 512 + h * 64 + c * 8);
    }
    for (int task = tid; task < 96 * 8; task += 384) {
        const int r = task >> 3, c = task & 7;
        uint4 dv = *(const uint4*)(vbuf + (base + (size_t)r * stride) * 512 + h * 64 + c * 8);
        const u16* e = (const u16*)&dv;
#pragma unroll
        for (int j = 0; j < 8; ++j) VT[c * 8 + j][r] = e[j];
    }
    const u16* qp = q + (base + (size_t)(16 * w + fr) * stride) * 512 + h * 64;
    bf16x8 aq0 = *(const bf16x8*)(qp + fk);
    bf16x8 aq1 = *(const bf16x8*)(qp + 32 + fk);
    __syncthreads();

    f32x4 s[6] = {};
#pragma unroll
    for (int fc = 0; fc < 6; ++fc) {
        bf16x8 b0 = *(const bf16x8*)&Ks[fc * 16 + fr][fk];
        bf16x8 b1 = *(const bf16x8*)&Ks[fc * 16 + fr][32 + fk];
        s[fc] = __builtin_amdgcn_mfma_f32_16x16x32_bf16(aq0, b0, s[fc], 0, 0, 0);
        s[fc] = __builtin_amdgcn_mfma_f32_16x16x32_bf16(aq1, b1, s[fc], 0, 0, 0);
    }
    float mrow[4], lrow[4];
#pragma unroll
    for (int e = 0; e < 4; ++e) {
        float mx = s[0][e];
#pragma unroll
        for (int fc = 1; fc < 6; ++fc) mx = fmaxf(mx, s[fc][e]);
#pragma unroll
        for (int off = 1; off < 16; off <<= 1) mx = fmaxf(mx, __shfl_xor(mx, off));
        mrow[e] = mx * 0.125f;
        lrow[e] = 0.f;
    }
    const int e0 = (l >> 4) * 4;
#pragma unroll
    for (int fc = 0; fc < 6; ++fc) {
#pragma unroll
        for (int e = 0; e < 4; ++e) {
            const float p = __expf(fmaf(s[fc][e], 0.125f, -mrow[e]));
            lrow[e] += p;
            Ps[16 * w + e0 + e][fc * 16 + fr] = f2bf(p);
        }
    }
#pragma unroll
    for (int e = 0; e < 4; ++e)
#pragma unroll
        for (int off = 1; off < 16; off <<= 1) lrow[e] += __shfl_xor(lrow[e], off);

    __syncthreads();

    f32x4 oacc[4] = {};
#pragma unroll
    for (int ks = 0; ks < 3; ++ks) {
        bf16x8 ap = *(const bf16x8*)&Ps[16 * w + fr][ks * 32 + fk];
#pragma unroll
        for (int j = 0; j < 4; ++j) {
            bf16x8 bv = *(const bf16x8*)&VT[j * 16 + fr][ks * 32 + fk];
            oacc[j] = __builtin_amdgcn_mfma_f32_16x16x32_bf16(ap, bv, oacc[j], 0, 0, 0);
        }
    }
    float mk[4];
#pragma unroll
    for (int e = 0; e < 4; ++e) {
        const size_t qrow = base + (size_t)(16 * w + e0 + e) * stride;
        mk[e] = mask[qrow] / lrow[e];
    }
#pragma unroll
    for (int j = 0; j < 4; ++j)
#pragma unroll
        for (int e = 0; e < 4; ++e) {
            const size_t qrow = base + (size_t)(16 * w + e0 + e) * stride;
            out[qrow * 512 + h * 64 + j * 16 + fr] = f2bf(oacc[j][e] * mk[e]);
        }
}

// ---------------- residual add + LayerNorm: 4 rows/block, one wave per row ----------------
template<typename TA, typename TB, typename TO>
__global__ __launch_bounds__(256)
void add_ln(const TA* __restrict__ a, const TB* __restrict__ bsrc,
            const float* __restrict__ g, const float* __restrict__ beta,
            TO* __restrict__ out)
{
    const size_t row = (size_t)blockIdx.x * 4 + (threadIdx.x >> 6);
    const int lane = threadIdx.x & 63;
    float ya[8], yb[8], y[8];
    load8(a + row * D_ + lane * 8, ya);
    load8(bsrc + row * D_ + lane * 8, yb);
    float sum = 0.f, sq = 0.f;
#pragma unroll
    for (int i = 0; i < 8; ++i) { y[i] = ya[i] + yb[i]; sum += y[i]; sq += y[i] * y[i]; }
#pragma unroll
    for (int off = 32; off >= 1; off >>= 1) {
        sum += __shfl_xor(sum, off);
        sq  += __shfl_xor(sq, off);
    }
    const float mean = sum * (1.f / D_);
    const float var  = sq * (1.f / D_) - mean * mean;
    const float rstd = rsqrtf(var + EPS_);
    const float* gp = g + lane * 8;
    const float* bp = beta + lane * 8;
    float o[8];
#pragma unroll
    for (int i = 0; i < 8; ++i) o[i] = (y[i] - mean) * rstd * gp[i] + bp[i];
    store8(out + row * D_ + lane * 8, o);
}

extern "C" void kernel_launch(void* const* d_in, const int* in_sizes, int n_in,
                              void* d_out, int out_size, void* d_ws, size_t ws_size,
                              hipStream_t stream)
{
    const float* x     = (const float*)d_in[0];
    const float* mask  = (const float*)d_in[1];
    const float* t_w   = (const float*)d_in[2];
    const float* t_b   = (const float*)d_in[3];
    const float* s_w   = (const float*)d_in[4];
    const float* s_b   = (const float*)d_in[5];
    const float* fc_w1 = (const float*)d_in[6];
    const float* fc_b1 = (const float*)d_in[7];
    const float* fc_w2 = (const float*)d_in[8];
    const float* fc_b2 = (const float*)d_in[9];
    const float* ln1_g = (const float*)d_in[10];
    const float* ln1_b = (const float*)d_in[11];
    const float* ln2_g = (const float*)d_in[12];
    const float* ln2_b = (const float*)d_in[13];

    const size_t PG = (size_t)NROWS * 512;
    const size_t WTC = (size_t)2048 * 512 * 2;    // tail (4 MB): 8xDD slots or fc WTs
    if (ws_size < (PG * 3 + WTC) * sizeof(u16)) return;
    u16* O0   = (u16*)d_out;                      // d_out pages (scratch until final LN)
    u16* O1   = O0 + PG;
    u16* WS0  = (u16*)d_ws;
    u16* WS1  = WS0 + PG;
    u16* WS2  = WS1 + PG;
    u16* TAIL = WS0 + 3 * PG;

    const dim3 gblk(256);
    const dim3 qkv3grid(12, NROWS / 192);         // 2304 blocks = 9 exact rounds (2/CU)
    const dim3 ss3grid(4, NROWS / 192);           // 768 blocks
    const dim3 h3grid(16, 18432 / 192);           // 1536 blocks
    const dim3 ff3grid(4, 18432 / 192);           // 384 blocks (fully resident)
    const dim3 lngrid(NROWS / 4);

    // x -> bf16 (WS2 = xb, persists through LN1)
    cvt_f32_bf16<<<dim3(2048), gblk, 0, stream>>>(x, WS2, (long)(PG / 8));
    // weight prep: slots [t0^T,t1^T,t2^T, t3 PLAIN, s0^T,s1^T,s2^T,s3^T]
    tconv8<<<dim3(16, 16, 8), gblk, 0, stream>>>(t_w, s_w, TAIL);
    // time QKV: q->O0, k->WS0, v->WS1 (reads slots 0-2)
    gemm3<0, u16><<<qkv3grid, dim3(512), 0, stream>>>(
        WS2, TAIL, t_b, O0, WS0, WS1, 512, 512, 512, 512, 9);
    // fused weights: WTf[1536][512] = WTs_{0..2} @ t_w3(plain) -> slots 0-2 (dead after qkv)
    gemm2<2, false, u16><<<dim3(4, 12), gblk, 0, stream>>>(
        TAIL + (size_t)4 * DD_, TAIL + (size_t)3 * DD_, nullptr, TAIL, 512, 512, 512, 512);
    // fused bias -> fp32[1536] at slot-3 bytes
    float* fb = (float*)(TAIL + (size_t)3 * DD_);
    fbias_k<<<dim3(6), gblk, 0, stream>>>(TAIL + (size_t)4 * DD_, t_b + 3 * 512, s_b, fb);
    // time attention: (O0,WS0,WS1) -> O0
    attn_mfma<<<dim3(B_ * H_ * 96), dim3(384), 0, stream>>>(O0, WS0, WS1, mask, O0, 1);
    // space QKV directly from time-attn output (tt GEMM fused away)
    gemm3<0, u16><<<qkv3grid, dim3(512), 0, stream>>>(
        O0, TAIL, fb, O1, WS0, WS1, 512, 512, 512, 512, 9);
    // space attention: (O1,WS0,WS1) -> O0
    attn_mfma<<<dim3(B_ * H_ * 96), dim3(384), 0, stream>>>(O1, WS0, WS1, mask, O0, 0);
    // ss projection: O0 @ s_w3 -> O1 (slot 7)
    gemm3<0, u16><<<ss3grid, dim3(512), 0, stream>>>(
        O0, TAIL + (size_t)7 * DD_, s_b + 3 * 512, O1, O1, O1, 512, 512, 512, 512, 30);
    // LN1: x1 = LN(xb + ss) -> WS2 in-place
    add_ln<u16, u16, u16><<<lngrid, gblk, 0, stream>>>(WS2, O1, ln1_g, ln1_b, WS2);
    // fc WTs -> tail (all slots dead now)
    u16* WT1f = TAIL;                             // fc_w1^T (2048 x 512)
    u16* WT2f = TAIL + (size_t)2048 * 512;        // fc_w2^T (512 x 2048)
    tconv<<<dim3(64, 16), gblk, 0, stream>>>(fc_w1, WT1f, 512, 2048);
    tconv<<<dim3(16, 64), gblk, 0, stream>>>(fc_w2, WT2f, 2048, 512);
    // ---- FFN row-split: per half, h fills d_out (2048-wide), single-pass ff -> WS1 ----
    for (int r = 0; r < 2; ++r) {
        const size_t off = (size_t)r * 18432;
        // h = leaky(x1 @ W1 + b1): [18432][2048] -> O0 (ldc 2048)
        gemm3<1, u16><<<h3grid, dim3(512), 0, stream>>>(
            WS2 + off * 512, WT1f, fc_b1, O0, O0, O0, 512, 512, 512, 2048, 30);
        // ff = h @ W2 + b2: K=2048 single pass (reads d_out, writes d_ws: disjoint)
        gemm3<0, u16><<<ff3grid, dim3(512), 0, stream>>>(
            O0, WT2f, fc_b2, WS1 + off * 512, WS1 + off * 512, WS1 + off * 512,
            2048, 2048, 2048, 512, 30);
    }
    // LN2: out = LN(x1 + ff) -> fp32 d_out (sources WS2/WS1 in d_ws only)
    add_ln<u16, u16, float><<<lngrid, gblk, 0, stream>>>(
        WS2, WS1, ln2_g, ln2_b, (float*)d_out);
}

// Round 15
// 467.556 us; speedup vs baseline: 1.2368x; 1.0527x over previous
//
#include <hip/hip_runtime.h>
#include <hip/hip_bf16.h>

#define B_ 4
#define S_ 96
#define T_ 96
#define D_ 512
#define H_ 8
#define FF_ 2048
#define NROWS (B_*S_*T_)   // 36864
#define EPS_ 1e-5f
#define NEG_ 0.01f
#define DD_ (512*512)

typedef unsigned short u16;   // bf16 bits
typedef __attribute__((ext_vector_type(8))) short bf16x8;
typedef __attribute__((ext_vector_type(4))) float f32x4;
typedef __attribute__((address_space(1))) const unsigned glb_u32;
typedef __attribute__((address_space(3))) unsigned lds_u32;

__device__ __forceinline__ float bf(u16 u) { return __uint_as_float(((unsigned)u) << 16); }
__device__ __forceinline__ u16 f2bf(float f) {
    __hip_bfloat16 h = __float2bfloat16(f);
    return *reinterpret_cast<u16*>(&h);
}
__device__ __forceinline__ float blo(unsigned v) { return __uint_as_float(v << 16); }
__device__ __forceinline__ float bhi(unsigned v) { return __uint_as_float(v & 0xffff0000u); }

__device__ __forceinline__ float cvt_ld(float x) { return x; }
__device__ __forceinline__ float cvt_ld(u16 x)  { return bf(x); }
__device__ __forceinline__ void cvt_st(float* p, float v) { *p = v; }
__device__ __forceinline__ void cvt_st(u16* p, float v)   { *p = f2bf(v); }

__device__ __forceinline__ void load8(const float* p, float* y) {
    float4 a = *(const float4*)p, b = *(const float4*)(p + 4);
    y[0]=a.x; y[1]=a.y; y[2]=a.z; y[3]=a.w; y[4]=b.x; y[5]=b.y; y[6]=b.z; y[7]=b.w;
}
__device__ __forceinline__ void load8(const u16* p, float* y) {
    uint4 u = *(const uint4*)p;
    y[0]=blo(u.x); y[1]=bhi(u.x); y[2]=blo(u.y); y[3]=bhi(u.y);
    y[4]=blo(u.z); y[5]=bhi(u.z); y[6]=blo(u.w); y[7]=bhi(u.w);
}
__device__ __forceinline__ void store8(float* p, const float* y) {
    *(float4*)p       = make_float4(y[0], y[1], y[2], y[3]);
    *(float4*)(p + 4) = make_float4(y[4], y[5], y[6], y[7]);
}
__device__ __forceinline__ void store8(u16* p, const float* y) {
    ushort4 a, b;
    a.x = f2bf(y[0]); a.y = f2bf(y[1]); a.z = f2bf(y[2]); a.w = f2bf(y[3]);
    b.x = f2bf(y[4]); b.y = f2bf(y[5]); b.z = f2bf(y[6]); b.w = f2bf(y[7]);
    *(ushort4*)p = a; *(ushort4*)(p + 4) = b;
}

// ---------------- fp32 -> bf16 elementwise (grid-stride) ----------------
__global__ __launch_bounds__(256)
void cvt_f32_bf16(const float* __restrict__ in, u16* __restrict__ out, long n8)
{
    for (long i = (long)blockIdx.x * 256 + threadIdx.x; i < n8; i += (long)gridDim.x * 256) {
        float y[8];
        load8(in + i * 8, y);
        store8(out + i * 8, y);
    }
}

// ---------------- transpose + convert (generic) ----------------
__global__ __launch_bounds__(256)
void tconv(const float* __restrict__ in, u16* __restrict__ out, int R, int C)
{
    __shared__ float t[32][33];
    const int c0 = blockIdx.x * 32, r0 = blockIdx.y * 32;
    const int tr = threadIdx.x >> 3, c4 = (threadIdx.x & 7) * 4;
    float4 v = *(const float4*)(in + (size_t)(r0 + tr) * C + c0 + c4);
    t[tr][c4] = v.x; t[tr][c4 + 1] = v.y; t[tr][c4 + 2] = v.z; t[tr][c4 + 3] = v.w;
    __syncthreads();
    const int oc = tr, r4 = c4;
    ushort4 u;
    u.x = f2bf(t[r4 + 0][oc]); u.y = f2bf(t[r4 + 1][oc]);
    u.z = f2bf(t[r4 + 2][oc]); u.w = f2bf(t[r4 + 3][oc]);
    *(ushort4*)(out + (size_t)(c0 + oc) * R + r0 + r4) = u;
}

// ---------------- batched 512x512 weight prep -> tail ----------------
// slots [t0^T, t1^T, t2^T, t3 PLAIN, s0^T, s1^T, s2^T, s3^T]
__global__ __launch_bounds__(256)
void tconv8(const float* __restrict__ t_w, const float* __restrict__ s_w,
            u16* __restrict__ out)
{
    __shared__ float t[32][33];
    const int z = blockIdx.z;
    const float* in = (z < 4) ? (t_w + (size_t)z * DD_) : (s_w + (size_t)(z - 4) * DD_);
    u16* o = out + (size_t)z * DD_;
    const int c0 = blockIdx.x * 32, r0 = blockIdx.y * 32;
    const int tr = threadIdx.x >> 3, c4 = (threadIdx.x & 7) * 4;
    float4 v = *(const float4*)(in + (size_t)(r0 + tr) * 512 + c0 + c4);
    if (z == 3) {   // plain convert-copy
        ushort4 u;
        u.x = f2bf(v.x); u.y = f2bf(v.y); u.z = f2bf(v.z); u.w = f2bf(v.w);
        *(ushort4*)(o + (size_t)(r0 + tr) * 512 + c0 + c4) = u;
        return;
    }
    t[tr][c4] = v.x; t[tr][c4 + 1] = v.y; t[tr][c4 + 2] = v.z; t[tr][c4 + 3] = v.w;
    __syncthreads();
    const int oc = tr, r4 = c4;
    ushort4 u;
    u.x = f2bf(t[r4 + 0][oc]); u.y = f2bf(t[r4 + 1][oc]);
    u.z = f2bf(t[r4 + 2][oc]); u.w = f2bf(t[r4 + 3][oc]);
    *(ushort4*)(o + (size_t)(c0 + oc) * 512 + r0 + r4) = u;
}

// ---------------- fused bias: fb[j] = s_b[j] + dot(WTs[j][:], t_b3) ----------------
__global__ __launch_bounds__(256)
void fbias_k(const u16* __restrict__ WTs, const float* __restrict__ tb3,
             const float* __restrict__ sb, float* __restrict__ fb)
{
    const int j = blockIdx.x * 256 + threadIdx.x;   // 0..1535
    const u16* row = WTs + (size_t)j * 512;
    float acc = sb[j];
    for (int k = 0; k < 512; k += 8) {
        float y[8], t[8];
        load8(row + k, y);
        load8(tb3 + k, t);
        acc += y[0]*t[0] + y[1]*t[1] + y[2]*t[2] + y[3]*t[3]
             + y[4]*t[4] + y[5]*t[5] + y[6]*t[6] + y[7]*t[7];
    }
    fb[j] = acc;
}

// ======== 128^2 GEMM (verified rounds 6-14): single-buffer 32 KB,
// XOR bank-deswizzle (both-sides), XCD-chunked grid swizzle ========
#define GEMM_PRE()                                                              \
    const int tid = threadIdx.x;                                                \
    const int w = tid >> 6, l = tid & 63;                                       \
    const int wr = w >> 1, wc = w & 1;                                          \
    const unsigned gx = gridDim.x;                                              \
    const unsigned nwg = gx * gridDim.y;                                        \
    unsigned f = blockIdx.y * gx + blockIdx.x;                                  \
    f = (f & 7) * (nwg >> 3) + (f >> 3);                                        \
    const int lrow = l >> 3;                                                    \
    const int swz8 = (((l & 7) ^ lrow) << 3);                                   \
    const int fr16 = l & 15;                                                    \
    const int kq = l >> 4;

#define GEMM_COMPUTE()                                                          \
    _Pragma("unroll")                                                           \
    for (int kk = 0; kk < 2; ++kk) {                                            \
        const int sw = ((((kk << 2) | kq)) ^ (fr16 & 7)) << 3;                  \
        bf16x8 af[4], bfr[4];                                                   \
        _Pragma("unroll")                                                       \
        for (int i = 0; i < 4; ++i)                                             \
            af[i] = *(bf16x8*)&As[(wr * 64 + i * 16 + fr16) * 64 + sw];         \
        _Pragma("unroll")                                                       \
        for (int j = 0; j < 4; ++j)                                             \
            bfr[j] = *(bf16x8*)&Bs[(wc * 64 + j * 16 + fr16) * 64 + sw];        \
        _Pragma("unroll")                                                       \
        for (int i = 0; i < 4; ++i)                                             \
            _Pragma("unroll")                                                   \
            for (int j = 0; j < 4; ++j)                                         \
                acc[i][j] = __builtin_amdgcn_mfma_f32_16x16x32_bf16(af[i], bfr[j], acc[i][j], 0, 0, 0); \
    }

// ACT: 0 = bias, 1 = bias+leaky, 2 = no-bias
template<int ACT, bool ACC, typename TC>
__global__ __launch_bounds__(256)
void gemm2(const u16* __restrict__ A, const u16* __restrict__ WT,
           const float* __restrict__ bias, TC* __restrict__ C,
           int K, int lda, int ldwt, int ldc)
{
    __shared__ u16 As[128 * 64];
    __shared__ u16 Bs[128 * 64];
    GEMM_PRE();
    const int row0 = (int)(f / gx) * 128, col0 = (int)(f % gx) * 128;
    f32x4 acc[4][4] = {};

    for (int kt = 0; kt < K; kt += 64) {
#pragma unroll
        for (int j = 0; j < 4; ++j) {
            const int line = w * 32 + j * 8;
            const u16* asrc = A  + (size_t)(row0 + line + lrow) * lda  + kt + swz8;
            const u16* bsrc = WT + (size_t)(col0 + line + lrow) * ldwt + kt + swz8;
            __builtin_amdgcn_global_load_lds((glb_u32*)asrc, (lds_u32*)&As[line * 64], 16, 0, 0);
            __builtin_amdgcn_global_load_lds((glb_u32*)bsrc, (lds_u32*)&Bs[line * 64], 16, 0, 0);
        }
        __syncthreads();
        GEMM_COMPUTE();
        __syncthreads();
    }
    const int crow = kq * 4;
#pragma unroll
    for (int i = 0; i < 4; ++i)
#pragma unroll
        for (int j = 0; j < 4; ++j) {
            const int col = col0 + wc * 64 + j * 16 + fr16;
            const float bv = (ACC || ACT == 2) ? 0.f : bias[col];
#pragma unroll
            for (int e = 0; e < 4; ++e) {
                const size_t r = (size_t)(row0 + wr * 64 + i * 16 + crow + e);
                TC* cp = &C[r * (size_t)ldc + col];
                float v = acc[i][j][e] + bv;
                if (ACC) v += cvt_ld(*cp);
                if (ACT == 1) v = (v >= 0.f) ? v : NEG_ * v;
                cvt_st(cp, v);
            }
        }
}

// ================= gemm3 (r13/r14 verified + 2-barrier variant): 192x128, BK=64,
// dbuf 80 KB, 2 blocks/CU. Stage next tile (5 gloads), counted vmcnt(5), gate
// barrier; kk0 {ds_read; setprio; 12 MFMA}; kk1 {ds_read; barrier; setprio; 12 MFMA}.
// kk1's barrier keeps all waves' tile-t ds_reads issued before any t+1 stage.
template<int ACT, typename TC>
__global__ __launch_bounds__(512)
void gemm3(const u16* __restrict__ A, const u16* __restrict__ WT,
           const float* __restrict__ bias,
           TC* __restrict__ p0, TC* __restrict__ p1, TC* __restrict__ p2,
           int K, int lda, int ldwt, int ldc, int pgshift)
{
    __shared__ u16 lds[40960];   // 80 KB: A dbuf 2x12288 @0, B dbuf 2x8192 @24576
    const int tid = threadIdx.x;
    const int w = tid >> 6, l = tid & 63;
    const int wr = w >> 1, wc = w & 1;
    const unsigned gx = gridDim.x;
    const unsigned nwg = gx * gridDim.y;
    unsigned f = blockIdx.y * gx + blockIdx.x;
    f = (f & 7) * (nwg >> 3) + (f >> 3);
    const int row0 = (int)(f / gx) * 192, colg0 = (int)(f % gx) * 128;
    const int lrow = l >> 3;
    const int swz8 = (((l & 7) ^ lrow) << 3);
    const int fr16 = l & 15;
    const int kq = l >> 4;

    f32x4 acc[3][4] = {};
    const int NT = K >> 6;

    auto stage = [&](int buf, int kt) {
        u16* Ad = lds + buf * 12288;
        u16* Bd = lds + 24576 + buf * 8192;
#pragma unroll
        for (int P = 0; P < 3; ++P) {                 // A: 192 lines in 3 positions
            const int lineb = P * 64 + w * 8;         // wave-uniform dest line
            const u16* asrc = A + (size_t)(row0 + lineb + lrow) * lda + kt + swz8;
            __builtin_amdgcn_global_load_lds((glb_u32*)asrc, (lds_u32*)&Ad[lineb * 64], 16, 0, 0);
        }
#pragma unroll
        for (int P = 0; P < 2; ++P) {                 // B: 128 lines in 2 positions
            const int lineb = P * 64 + w * 8;
            const u16* bsrc = WT + (size_t)(colg0 + lineb + lrow) * ldwt + kt + swz8;
            __builtin_amdgcn_global_load_lds((glb_u32*)bsrc, (lds_u32*)&Bd[lineb * 64], 16, 0, 0);
        }
    };

    stage(0, 0);
    for (int t = 0; t < NT; ++t) {
        const int cur = t & 1;
        if (t + 1 < NT) {
            stage(cur ^ 1, (t + 1) << 6);
            asm volatile("s_waitcnt vmcnt(5)" ::: "memory");   // prev tile's 5 landed
        } else {
            asm volatile("s_waitcnt vmcnt(0)" ::: "memory");
        }
        __builtin_amdgcn_s_barrier();                          // gate: buf[cur] published
        const u16* Ab = lds + cur * 12288;
        const u16* Bb = lds + 24576 + cur * 8192;
#pragma unroll
        for (int kk = 0; kk < 2; ++kk) {
            const int sw = ((((kk << 2) | kq)) ^ (fr16 & 7)) << 3;
            bf16x8 bq[4], af[3];
#pragma unroll
            for (int j = 0; j < 4; ++j)
                bq[j] = *(bf16x8*)&Bb[(wc * 64 + j * 16 + fr16) * 64 + sw];
#pragma unroll
            for (int i = 0; i < 3; ++i)
                af[i] = *(bf16x8*)&Ab[(wr * 48 + i * 16 + fr16) * 64 + sw];
            if (kk == 1) __builtin_amdgcn_s_barrier();         // tile-t reads all issued
            __builtin_amdgcn_s_setprio(1);
#pragma unroll
            for (int i = 0; i < 3; ++i)
#pragma unroll
                for (int j = 0; j < 4; ++j)
                    acc[i][j] = __builtin_amdgcn_mfma_f32_16x16x32_bf16(
                        af[i], bq[j], acc[i][j], 0, 0, 0);
            __builtin_amdgcn_s_setprio(0);
        }
    }
    // epilogue
    const int crow = kq * 4;
#pragma unroll
    for (int i = 0; i < 3; ++i)
#pragma unroll
        for (int j = 0; j < 4; ++j) {
            const int colg = colg0 + wc * 64 + j * 16 + fr16;
            TC* Cb = (((unsigned)colg >> pgshift) == 0) ? p0
                   : (((unsigned)colg >> pgshift) == 1) ? p1 : p2;
            const int col = colg & ((1 << pgshift) - 1);
            const float bv = bias[colg];
#pragma unroll
            for (int e = 0; e < 4; ++e) {
                const size_t r = (size_t)(row0 + wr * 48 + i * 16 + crow + e);
                float v = acc[i][j][e] + bv;
                if (ACT == 1) v = (v >= 0.f) ? v : NEG_ * v;
                cvt_st(&Cb[r * (size_t)ldc + col], v);
            }
        }
}

// ---------------- MFMA attention: Ks/Ps LDS union -> 33.3 KB, 4 blocks/CU ----------------
// Phase ordering: stage Ks,VT | sync | QK^T reads Ks | sync (all Ks reads done) |
// Ps writes overlay Ks region | sync | PV reads Ps,VT.
__global__ __launch_bounds__(384, 6)
void attn_mfma(const u16* __restrict__ q, const u16* __restrict__ kbuf,
               const u16* __restrict__ vbuf, const float* __restrict__ mask,
               u16* __restrict__ out, int time_axis)
{
    __shared__ __align__(16) u16 sh[96 * 104 + 64 * 104];   // union(Ks,Ps) + VT
    u16 (*Ks)[72]  = (u16(*)[72])sh;            // QK phase: stride 144B (9 chunks, odd)
    u16 (*Ps)[104] = (u16(*)[104])sh;           // PV phase overlay: stride 208B (13 chunks)
    u16 (*VT)[104] = (u16(*)[104])(sh + 96 * 104);
    const int g = blockIdx.x;
    const int h = g & 7;
    const int bs = g >> 3;
    const int b = bs / 96, st = bs % 96;
    const size_t base   = time_axis ? ((size_t)(b * 96 + st) * 96) : ((size_t)b * 9216 + st);
    const size_t stride = time_axis ? 1 : 96;
    const int tid = threadIdx.x;
    const int w = tid / 64, l = tid & 63;
    const int fr = l & 15, fk = (l >> 4) * 8;

    for (int task = tid; task < 96 * 8; task += 384) {
        const int r = task >> 3, c = task & 7;
        *(uint4*)&Ks[r][c * 8] =
            *(const uint4*)(kbuf + (base + (size_t)r * stride) * 512 + h * 64 + c * 8);
    }
    for (int task = tid; task < 96 * 8; task += 384) {
        const int r = task >> 3, c = task & 7;
        uint4 dv = *(const uint4*)(vbuf + (base + (size_t)r * stride) * 512 + h * 64 + c * 8);
        const u16* e = (const u16*)&dv;
#pragma unroll
        for (int j = 0; j < 8; ++j) VT[c * 8 + j][r] = e[j];
    }
    const u16* qp = q + (base + (size_t)(16 * w + fr) * stride) * 512 + h * 64;
    bf16x8 aq0 = *(const bf16x8*)(qp + fk);
    bf16x8 aq1 = *(const bf16x8*)(qp + 32 + fk);
    __syncthreads();

    f32x4 s[6] = {};
#pragma unroll
    for (int fc = 0; fc < 6; ++fc) {
        bf16x8 b0 = *(const bf16x8*)&Ks[fc * 16 + fr][fk];
        bf16x8 b1 = *(const bf16x8*)&Ks[fc * 16 + fr][32 + fk];
        s[fc] = __builtin_amdgcn_mfma_f32_16x16x32_bf16(aq0, b0, s[fc], 0, 0, 0);
        s[fc] = __builtin_amdgcn_mfma_f32_16x16x32_bf16(aq1, b1, s[fc], 0, 0, 0);
    }
    float mrow[4], lrow[4];
#pragma unroll
    for (int e = 0; e < 4; ++e) {
        float mx = s[0][e];
#pragma unroll
        for (int fc = 1; fc < 6; ++fc) mx = fmaxf(mx, s[fc][e]);
#pragma unroll
        for (int off = 1; off < 16; off <<= 1) mx = fmaxf(mx, __shfl_xor(mx, off));
        mrow[e] = mx * 0.125f;
        lrow[e] = 0.f;
    }
    __syncthreads();   // all Ks reads complete before Ps overlays the same LDS

    const int e0 = (l >> 4) * 4;
#pragma unroll
    for (int fc = 0; fc < 6; ++fc) {
#pragma unroll
        for (int e = 0; e < 4; ++e) {
            const float p = __expf(fmaf(s[fc][e], 0.125f, -mrow[e]));
            lrow[e] += p;
            Ps[16 * w + e0 + e][fc * 16 + fr] = f2bf(p);
        }
    }
#pragma unroll
    for (int e = 0; e < 4; ++e)
#pragma unroll
        for (int off = 1; off < 16; off <<= 1) lrow[e] += __shfl_xor(lrow[e], off);

    __syncthreads();

    f32x4 oacc[4] = {};
#pragma unroll
    for (int ks = 0; ks < 3; ++ks) {
        bf16x8 ap = *(const bf16x8*)&Ps[16 * w + fr][ks * 32 + fk];
#pragma unroll
        for (int j = 0; j < 4; ++j) {
            bf16x8 bv = *(const bf16x8*)&VT[j * 16 + fr][ks * 32 + fk];
            oacc[j] = __builtin_amdgcn_mfma_f32_16x16x32_bf16(ap, bv, oacc[j], 0, 0, 0);
        }
    }
    float mk[4];
#pragma unroll
    for (int e = 0; e < 4; ++e) {
        const size_t qrow = base + (size_t)(16 * w + e0 + e) * stride;
        mk[e] = mask[qrow] / lrow[e];
    }
#pragma unroll
    for (int j = 0; j < 4; ++j)
#pragma unroll
        for (int e = 0; e < 4; ++e) {
            const size_t qrow = base + (size_t)(16 * w + e0 + e) * stride;
            out[qrow * 512 + h * 64 + j * 16 + fr] = f2bf(oacc[j][e] * mk[e]);
        }
}

// ---------------- residual add + LayerNorm: 4 rows/block, one wave per row ----------------
template<typename TA, typename TB, typename TO>
__global__ __launch_bounds__(256)
void add_ln(const TA* __restrict__ a, const TB* __restrict__ bsrc,
            const float* __restrict__ g, const float* __restrict__ beta,
            TO* __restrict__ out)
{
    const size_t row = (size_t)blockIdx.x * 4 + (threadIdx.x >> 6);
    const int lane = threadIdx.x & 63;
    float ya[8], yb[8], y[8];
    load8(a + row * D_ + lane * 8, ya);
    load8(bsrc + row * D_ + lane * 8, yb);
    float sum = 0.f, sq = 0.f;
#pragma unroll
    for (int i = 0; i < 8; ++i) { y[i] = ya[i] + yb[i]; sum += y[i]; sq += y[i] * y[i]; }
#pragma unroll
    for (int off = 32; off >= 1; off >>= 1) {
        sum += __shfl_xor(sum, off);
        sq  += __shfl_xor(sq, off);
    }
    const float mean = sum * (1.f / D_);
    const float var  = sq * (1.f / D_) - mean * mean;
    const float rstd = rsqrtf(var + EPS_);
    const float* gp = g + lane * 8;
    const float* bp = beta + lane * 8;
    float o[8];
#pragma unroll
    for (int i = 0; i < 8; ++i) o[i] = (y[i] - mean) * rstd * gp[i] + bp[i];
    store8(out + row * D_ + lane * 8, o);
}

extern "C" void kernel_launch(void* const* d_in, const int* in_sizes, int n_in,
                              void* d_out, int out_size, void* d_ws, size_t ws_size,
                              hipStream_t stream)
{
    const float* x     = (const float*)d_in[0];
    const float* mask  = (const float*)d_in[1];
    const float* t_w   = (const float*)d_in[2];
    const float* t_b   = (const float*)d_in[3];
    const float* s_w   = (const float*)d_in[4];
    const float* s_b   = (const float*)d_in[5];
    const float* fc_w1 = (const float*)d_in[6];
    const float* fc_b1 = (const float*)d_in[7];
    const float* fc_w2 = (const float*)d_in[8];
    const float* fc_b2 = (const float*)d_in[9];
    const float* ln1_g = (const float*)d_in[10];
    const float* ln1_b = (const float*)d_in[11];
    const float* ln2_g = (const float*)d_in[12];
    const float* ln2_b = (const float*)d_in[13];

    const size_t PG = (size_t)NROWS * 512;
    const size_t WTC = (size_t)2048 * 512 * 2;    // tail (4 MB): 8xDD slots or fc WTs
    if (ws_size < (PG * 3 + WTC) * sizeof(u16)) return;
    u16* O0   = (u16*)d_out;                      // d_out pages (scratch until final LN)
    u16* O1   = O0 + PG;
    u16* WS0  = (u16*)d_ws;
    u16* WS1  = WS0 + PG;
    u16* WS2  = WS1 + PG;
    u16* TAIL = WS0 + 3 * PG;

    const dim3 gblk(256);
    const dim3 qkv3grid(12, NROWS / 192);         // 2304 blocks
    const dim3 ss3grid(4, NROWS / 192);           // 768 blocks
    const dim3 h3grid(16, 18432 / 192);           // 1536 blocks
    const dim3 ff3grid(4, 18432 / 192);           // 384 blocks
    const dim3 lngrid(NROWS / 4);

    // x -> bf16 (WS2 = xb, persists through LN1)
    cvt_f32_bf16<<<dim3(2048), gblk, 0, stream>>>(x, WS2, (long)(PG / 8));
    // weight prep: slots [t0^T,t1^T,t2^T, t3 PLAIN, s0^T,s1^T,s2^T,s3^T]
    tconv8<<<dim3(16, 16, 8), gblk, 0, stream>>>(t_w, s_w, TAIL);
    // time QKV: q->O0, k->WS0, v->WS1 (reads slots 0-2)
    gemm3<0, u16><<<qkv3grid, dim3(512), 0, stream>>>(
        WS2, TAIL, t_b, O0, WS0, WS1, 512, 512, 512, 512, 9);
    // fused weights: WTf[1536][512] = WTs_{0..2} @ t_w3(plain) -> slots 0-2 (dead after qkv)
    gemm2<2, false, u16><<<dim3(4, 12), gblk, 0, stream>>>(
        TAIL + (size_t)4 * DD_, TAIL + (size_t)3 * DD_, nullptr, TAIL, 512, 512, 512, 512);
    // fused bias -> fp32[1536] at slot-3 bytes
    float* fb = (float*)(TAIL + (size_t)3 * DD_);
    fbias_k<<<dim3(6), gblk, 0, stream>>>(TAIL + (size_t)4 * DD_, t_b + 3 * 512, s_b, fb);
    // time attention: (O0,WS0,WS1) -> O0
    attn_mfma<<<dim3(B_ * H_ * 96), dim3(384), 0, stream>>>(O0, WS0, WS1, mask, O0, 1);
    // space QKV directly from time-attn output (tt GEMM fused away)
    gemm3<0, u16><<<qkv3grid, dim3(512), 0, stream>>>(
        O0, TAIL, fb, O1, WS0, WS1, 512, 512, 512, 512, 9);
    // space attention: (O1,WS0,WS1) -> O0
    attn_mfma<<<dim3(B_ * H_ * 96), dim3(384), 0, stream>>>(O1, WS0, WS1, mask, O0, 0);
    // ss projection: O0 @ s_w3 -> O1 (slot 7)
    gemm3<0, u16><<<ss3grid, dim3(512), 0, stream>>>(
        O0, TAIL + (size_t)7 * DD_, s_b + 3 * 512, O1, O1, O1, 512, 512, 512, 512, 30);
    // LN1: x1 = LN(xb + ss) -> WS2 in-place
    add_ln<u16, u16, u16><<<lngrid, gblk, 0, stream>>>(WS2, O1, ln1_g, ln1_b, WS2);
    // fc WTs -> tail (all slots dead now)
    u16* WT1f = TAIL;                             // fc_w1^T (2048 x 512)
    u16* WT2f = TAIL + (size_t)2048 * 512;        // fc_w2^T (512 x 2048)
    tconv<<<dim3(64, 16), gblk, 0, stream>>>(fc_w1, WT1f, 512, 2048);
    tconv<<<dim3(16, 64), gblk, 0, stream>>>(fc_w2, WT2f, 2048, 512);
    // ---- FFN row-split: per half, h fills d_out (2048-wide), single-pass ff -> WS1 ----
    for (int r = 0; r < 2; ++r) {
        const size_t off = (size_t)r * 18432;
        gemm3<1, u16><<<h3grid, dim3(512), 0, stream>>>(
            WS2 + off * 512, WT1f, fc_b1, O0, O0, O0, 512, 512, 512, 2048, 30);
        gemm3<0, u16><<<ff3grid, dim3(512), 0, stream>>>(
            O0, WT2f, fc_b2, WS1 + off * 512, WS1 + off * 512, WS1 + off * 512,
            2048, 2048, 2048, 512, 30);
    }
    // LN2: out = LN(x1 + ff) -> fp32 d_out (sources WS2/WS1 in d_ws only)
    add_ln<u16, u16, float><<<lngrid, gblk, 0, stream>>>(
        WS2, WS1, ln2_g, ln2_b, (float*)d_out);
}